// Round 10
// baseline (687.508 us; speedup 1.0000x reference)
//
#include <hip/hip_runtime.h>
#include <hip/hip_bf16.h>

#define NIMG 32
#define NPTS 300000
#define NL   64
#define NBOX 256

#define BANDS  8
#define BROWS  32          // NBOX / BANDS

__device__ __forceinline__ int rev8(int x) { return (int)(__brev((unsigned)x) >> 24); }

// LDS float atomic add -> ds_add_f32 (no rtn). ~4 cy per executed lane-op
// (HW throughput wall, measured R5-R9 across 3 impls & 3 occupancies).
__device__ __forceinline__ void lds_fadd(float* p, float v) {
    (void)__hip_atomic_fetch_add(p, v, __ATOMIC_RELAXED, __HIP_MEMORY_SCOPE_WORKGROUP);
}

// ---------------- zero fill (fallback path only) ----------------
__global__ __launch_bounds__(256) void zero_kernel(float4* p, int n4) {
    int i = blockIdx.x * 256 + threadIdx.x;
    if (i < n4) p[i] = make_float4(0.f, 0.f, 0.f, 0.f);
}

// ---------------- P0: per-image fused coefficients ----------------
// u_b[i] = R00*z_x[b][i] + R01*z_y[b][i] + R02*z_z[b][i]   (v_b with row 1)
// hdr[2b]   = (R00, R01, R02, shx+128)
// hdr[2b+1] = (R10, R11, R12, shy+128)
__global__ __launch_bounds__(256) void uvprep_kernel(
    const float* __restrict__ z_x, const float* __restrict__ z_y,
    const float* __restrict__ z_z, const float* __restrict__ R,
    const float* __restrict__ shifts,
    float2* __restrict__ uvbuf, float4* __restrict__ hdrbuf)
{
    int t = threadIdx.x;
    for (int e = t; e < NIMG * NL; e += 256) {
        int b = e >> 6, i = e & 63;
        const float* Rb = R + b * 9;
        float zx = z_x[b * NL + i], zy = z_y[b * NL + i], zz = z_z[b * NL + i];
        float u = Rb[0] * zx + Rb[1] * zy + Rb[2] * zz;
        float v = Rb[3] * zx + Rb[4] * zy + Rb[5] * zz;
        uvbuf[e] = make_float2(u, v);
    }
    if (t < NIMG) {
        const float* Rb = R + t * 9;
        hdrbuf[2 * t]     = make_float4(Rb[0], Rb[1], Rb[2], shifts[2 * t]     + 128.f);
        hdrbuf[2 * t + 1] = make_float4(Rb[3], Rb[4], Rb[5], shifts[2 * t + 1] + 128.f);
    }
}

// ---------------- P1: projection, 2 points/thread, no LDS ----------------
// px = basex + u_b . Zrow ; py = basey + v_b . Zrow
__global__ __launch_bounds__(256) void project2_kernel(
    const float* __restrict__ Zb, const float* __restrict__ coords,
    const float4* __restrict__ uv4,   // [NIMG][32]: (u2j, v2j, u2j+1, v2j+1)
    const float4* __restrict__ hdr,   // [NIMG*2]
    float2* __restrict__ pairs)
{
    int tid = threadIdx.x;
    int p0 = blockIdx.x * 512 + tid;
    int p1 = p0 + 256;
    bool v1 = p1 < NPTS;
    int q1 = v1 ? p1 : (NPTS - 1);
    if (p0 >= NPTS) return;   // can only happen in a fully-dead tail (never here)

    float4 za[16], zc[16];
    {
        const float4* Z0 = (const float4*)(Zb + (size_t)p0 * NL);
        const float4* Z1 = (const float4*)(Zb + (size_t)q1 * NL);
        #pragma unroll
        for (int i = 0; i < 16; ++i) { za[i] = Z0[i]; zc[i] = Z1[i]; }
    }
    float c0x = coords[3 * p0], c0y = coords[3 * p0 + 1], c0z = coords[3 * p0 + 2];
    float c1x = coords[3 * q1], c1y = coords[3 * q1 + 1], c1z = coords[3 * q1 + 2];

    for (int b = 0; b < NIMG; ++b) {
        float4 h0 = hdr[2 * b], h1 = hdr[2 * b + 1];
        float ax0 = fmaf(h0.x, c0x, fmaf(h0.y, c0y, fmaf(h0.z, c0z, h0.w)));
        float ay0 = fmaf(h1.x, c0x, fmaf(h1.y, c0y, fmaf(h1.z, c0z, h1.w)));
        float ax1 = fmaf(h0.x, c1x, fmaf(h0.y, c1y, fmaf(h0.z, c1z, h0.w)));
        float ay1 = fmaf(h1.x, c1x, fmaf(h1.y, c1y, fmaf(h1.z, c1z, h1.w)));
        const float4* ub = uv4 + b * 32;
        #pragma unroll
        for (int j = 0; j < 32; ++j) {
            float4 uv = ub[j];
            float4 zv0 = za[j >> 1];
            float4 zv1 = zc[j >> 1];
            float zA0 = (j & 1) ? zv0.z : zv0.x;
            float zB0 = (j & 1) ? zv0.w : zv0.y;
            float zA1 = (j & 1) ? zv1.z : zv1.x;
            float zB1 = (j & 1) ? zv1.w : zv1.y;
            ax0 = fmaf(uv.x, zA0, ax0);  ay0 = fmaf(uv.y, zA0, ay0);
            ax0 = fmaf(uv.z, zB0, ax0);  ay0 = fmaf(uv.w, zB0, ay0);
            ax1 = fmaf(uv.x, zA1, ax1);  ay1 = fmaf(uv.y, zA1, ay1);
            ax1 = fmaf(uv.z, zB1, ax1);  ay1 = fmaf(uv.w, zB1, ay1);
        }
        float2* pb = pairs + (size_t)b * NPTS;
        pb[p0] = make_float2(ax0, ay0);
        if (v1) pb[p1] = make_float2(ax1, ay1);
    }
}

// ---------------- P2: band splat, exclusive band ownership, plain-store flush ----------------
// Grid: id = band*32 + b  -> id % 8 == b % 8: an image's 8 band-readers share an XCD.
__global__ __launch_bounds__(512) void splat2_kernel(
    const float2* __restrict__ pairs, const float* __restrict__ weights,
    float* __restrict__ img)
{
    __shared__ float tile[BROWS * NBOX];   // 32 KB
    int tid = threadIdx.x;
    int id = blockIdx.x;
    int band = id >> 5;
    int b    = id & 31;

    float4* t4 = (float4*)tile;
    for (int i = tid; i < BROWS * NBOX / 4; i += 512)
        t4[i] = make_float4(0.f, 0.f, 0.f, 0.f);
    __syncthreads();

    const int y_lo = band * BROWS;
    const float2* pp = pairs + (size_t)b * NPTS;

    for (int i = 4 * tid; i < NPTS; i += 2048) {
        float4 q0 = *(const float4*)(pp + i);       // points i, i+1
        float4 q1 = *(const float4*)(pp + i + 2);   // points i+2, i+3
        float4 wv = *(const float4*)(weights + i);
        float pxa[4] = {q0.x, q0.z, q1.x, q1.z};
        float pya[4] = {q0.y, q0.w, q1.y, q1.w};
        float wa[4]  = {wv.x, wv.y, wv.z, wv.w};
        #pragma unroll
        for (int k = 0; k < 4; ++k) {
            float px = pxa[k], py = pya[k], w = wa[k];
            float x0 = floorf(px), y0 = floorf(py);
            float fx = px - x0, fy = py - y0;
            int xi0 = min(max((int)x0, 0), NBOX - 1);
            int yi0 = min(max((int)y0, 0), NBOX - 1);
            int xi1 = min(xi0 + 1, NBOX - 1);
            int yi1 = min(yi0 + 1, NBOX - 1);
            float w00 = w * (1.f - fx) * (1.f - fy);
            float w10 = w * fx * (1.f - fy);
            float w01 = w * (1.f - fx) * fy;
            float w11 = w * fx * fy;
            int r0 = yi0 - y_lo, r1 = yi1 - y_lo;
            if ((unsigned)r0 < BROWS) {
                lds_fadd(&tile[r0 * NBOX + xi0], w00);
                lds_fadd(&tile[r0 * NBOX + xi1], w10);
            }
            if ((unsigned)r1 < BROWS) {
                lds_fadd(&tile[r1 * NBOX + xi0], w01);
                lds_fadd(&tile[r1 * NBOX + xi1], w11);
            }
        }
    }
    __syncthreads();
    // exclusive band region -> plain vector store (no zero_kernel, no atomic flush)
    float4* ib4 = (float4*)(img + (size_t)b * NBOX * NBOX + (size_t)y_lo * NBOX);
    for (int i = tid; i < BROWS * NBOX / 4; i += 512)
        ib4[i] = t4[i];
}

// ---------------- fallback: fused splat with global atomics (small ws) ----------------
__global__ __launch_bounds__(256) void splat_kernel(
    const float* __restrict__ z_x, const float* __restrict__ z_y,
    const float* __restrict__ z_z, const float* __restrict__ Zb,
    const float* __restrict__ coords, const float* __restrict__ weights,
    const float* __restrict__ R, const float* __restrict__ shifts,
    float* __restrict__ img)
{
    __shared__ float s_z[3][NIMG][NL];
    __shared__ float s_R[NIMG][9];
    __shared__ float s_sh[NIMG][2];

    int tid = threadIdx.x;
    for (int i = tid; i < NIMG * NL; i += 256) {
        (&s_z[0][0][0])[i] = z_x[i];
        (&s_z[1][0][0])[i] = z_y[i];
        (&s_z[2][0][0])[i] = z_z[i];
    }
    for (int i = tid; i < NIMG * 9; i += 256) (&s_R[0][0])[i] = R[i];
    if (tid < NIMG * 2) (&s_sh[0][0])[tid] = shifts[tid];
    __syncthreads();

    int p = blockIdx.x * 256 + tid;
    if (p >= NPTS) return;

    float4 zr[16];
    const float4* Zr4 = (const float4*)(Zb + (size_t)p * NL);
    #pragma unroll
    for (int i = 0; i < 16; ++i) zr[i] = Zr4[i];

    float cx0 = coords[3 * p + 0];
    float cy0 = coords[3 * p + 1];
    float cz0 = coords[3 * p + 2];
    float w   = weights[p];

    for (int b = 0; b < NIMG; ++b) {
        const float4* zx4 = (const float4*)s_z[0][b];
        const float4* zy4 = (const float4*)s_z[1][b];
        const float4* zz4 = (const float4*)s_z[2][b];
        float dx = 0.f, dy = 0.f, dz = 0.f;
        #pragma unroll
        for (int i = 0; i < 16; ++i) {
            float4 a = zx4[i];
            dx += a.x * zr[i].x + a.y * zr[i].y + a.z * zr[i].z + a.w * zr[i].w;
            float4 bb = zy4[i];
            dy += bb.x * zr[i].x + bb.y * zr[i].y + bb.z * zr[i].z + bb.w * zr[i].w;
            float4 c = zz4[i];
            dz += c.x * zr[i].x + c.y * zr[i].y + c.z * zr[i].z + c.w * zr[i].w;
        }
        float cx = cx0 + dx, cy = cy0 + dy, cz = cz0 + dz;
        const float* Rb = s_R[b];
        float px = Rb[0] * cx + Rb[1] * cy + Rb[2] * cz + s_sh[b][0] + 128.0f;
        float py = Rb[3] * cx + Rb[4] * cy + Rb[5] * cz + s_sh[b][1] + 128.0f;

        float x0 = floorf(px), y0 = floorf(py);
        float fx = px - x0, fy = py - y0;
        int xi0 = min(max((int)x0, 0), NBOX - 1);
        int yi0 = min(max((int)y0, 0), NBOX - 1);
        int xi1 = min(xi0 + 1, NBOX - 1);
        int yi1 = min(yi0 + 1, NBOX - 1);

        float* ib = img + (size_t)b * NBOX * NBOX;
        unsafeAtomicAdd(ib + yi0 * NBOX + xi0, w * (1.f - fx) * (1.f - fy));
        unsafeAtomicAdd(ib + yi0 * NBOX + xi1, w * fx * (1.f - fy));
        unsafeAtomicAdd(ib + yi1 * NBOX + xi0, w * (1.f - fx) * fy);
        unsafeAtomicAdd(ib + yi1 * NBOX + xi1, w * fx * fy);
    }
}

// ---------------- 256-pt FFT helpers (AOS float2, LDS twiddle) ----------------
__device__ __forceinline__ void fft_dif_t(float2* s, const float2* tw, int t) {
    #pragma unroll
    for (int st = 7; st >= 0; --st) {
        int half = 1 << st;
        int j  = t & (half - 1);
        int i1 = ((t >> st) << (st + 1)) + j;
        int i2 = i1 + half;
        float2 a = s[i1], b = s[i2];
        float2 w = tw[j << (7 - st)];
        float dxr = a.x - b.x, dxi = a.y - b.y;
        s[i1] = make_float2(a.x + b.x, a.y + b.y);
        s[i2] = make_float2(w.x * dxr - w.y * dxi, w.x * dxi + w.y * dxr);
        __syncthreads();
    }
}

__device__ __forceinline__ void fft_dit_t(float2* s, const float2* tw, int t) {
    #pragma unroll
    for (int st = 0; st < 8; ++st) {
        int half = 1 << st;
        int j  = t & (half - 1);
        int i1 = ((t >> st) << (st + 1)) + j;
        int i2 = i1 + half;
        float2 a = s[i1], b = s[i2];
        float2 w = tw[j << (7 - st)];
        float cs = w.x, sn = -w.y;
        float tr = cs * b.x - sn * b.y;
        float ti = cs * b.y + sn * b.x;
        s[i1] = make_float2(a.x + tr, a.y + ti);
        s[i2] = make_float2(a.x - tr, a.y - ti);
        __syncthreads();
    }
}

// ---------------- SOA FFT helpers (8-col kernel) ----------------
__device__ __forceinline__ void fft_dif_soa(float* re, float* im, const float2* tw, int t) {
    #pragma unroll
    for (int st = 7; st >= 0; --st) {
        int half = 1 << st;
        int j  = t & (half - 1);
        int i1 = ((t >> st) << (st + 1)) + j;
        int i2 = i1 + half;
        float ar = re[i1], ai = im[i1], br = re[i2], bi = im[i2];
        float2 w = tw[j << (7 - st)];
        float dr = ar - br, di = ai - bi;
        re[i1] = ar + br;  im[i1] = ai + bi;
        re[i2] = w.x * dr - w.y * di;
        im[i2] = w.x * di + w.y * dr;
        __syncthreads();
    }
}

__device__ __forceinline__ void fft_dit_soa(float* re, float* im, const float2* tw, int t) {
    #pragma unroll
    for (int st = 0; st < 8; ++st) {
        int half = 1 << st;
        int j  = t & (half - 1);
        int i1 = ((t >> st) << (st + 1)) + j;
        int i2 = i1 + half;
        float ar = re[i1], ai = im[i1], br = re[i2], bi = im[i2];
        float2 w = tw[j << (7 - st)];
        float cs = w.x, sn = -w.y;
        float tr = cs * br - sn * bi;
        float ti = cs * bi + sn * br;
        re[i1] = ar + tr;  im[i1] = ai + ti;
        re[i2] = ar - tr;  im[i2] = ai - ti;
        __syncthreads();
    }
}

__device__ __forceinline__ void init_tw(float2* tw, int tid) {
    if (tid < 128) {
        float sn, cs;
        sincosf(-6.283185307179586f * (float)tid * (1.0f / 256.0f), &sn, &cs);
        tw[tid] = make_float2(cs, sn);
    }
}

// ---------------- Pass A: fused 5x5 blur + forward row FFT ----------------
__global__ __launch_bounds__(256) void fft_rows_fwd_blur_kernel(const float* __restrict__ img,
                                                                float2* __restrict__ freq)
{
    __shared__ float2 s[2][NBOX];
    __shared__ float  sb[2][NBOX];
    __shared__ float2 tw[128];
    int tid = threadIdx.x;
    int tx = tid & 127, ty = tid >> 7;
    init_tw(tw, tid);
    int row = blockIdx.x * 2 + ty;     // 0 .. B*N-1
    int b = row >> 8, y = row & (NBOX - 1);
    const float* ib = img + ((size_t)b << 16);
    const float gw[5] = {0.0544886845f, 0.2442013420f, 0.4026199469f,
                         0.2442013420f, 0.0544886845f};
    float acc0 = 0.f, acc1 = 0.f;
    #pragma unroll
    for (int dy = -2; dy <= 2; ++dy) {
        int yy = y + dy;
        if ((unsigned)yy < (unsigned)NBOX) {
            const float* rp = ib + yy * NBOX;
            acc0 += gw[dy + 2] * rp[tx];
            acc1 += gw[dy + 2] * rp[tx + 128];
        }
    }
    sb[ty][tx] = acc0;  sb[ty][tx + 128] = acc1;
    __syncthreads();
    float r0 = 0.f, r1 = 0.f;
    #pragma unroll
    for (int dx = -2; dx <= 2; ++dx) {
        int x0 = tx + dx, x1 = tx + 128 + dx;
        if ((unsigned)x0 < (unsigned)NBOX) r0 += gw[dx + 2] * sb[ty][x0];
        if ((unsigned)x1 < (unsigned)NBOX) r1 += gw[dx + 2] * sb[ty][x1];
    }
    s[ty][tx]       = make_float2(r0, 0.f);
    s[ty][tx + 128] = make_float2(r1, 0.f);
    __syncthreads();
    fft_dif_t(s[ty], tw, tx);
    float2* op = freq + (size_t)row * NBOX;
    op[tx]       = s[ty][tx];
    op[tx + 128] = s[ty][tx + 128];
}

// ---------------- Pass B: 8-column fused fwd-FFT * ctf * inv-FFT ----------------
__global__ __launch_bounds__(1024) void fft_cols_ctf8_kernel(float2* __restrict__ freq,
                                                             const float* __restrict__ ctf)
{
    __shared__ float  s_re[8][257];
    __shared__ float  s_im[8][257];
    __shared__ float2 tw[128];
    int tid = threadIdx.x;
    init_tw(tw, tid);
    int col = tid & 7, j = tid >> 3;          // j in 0..127
    int blk = blockIdx.x;
    int b = blk >> 5;
    int x = ((blk & 31) << 3) + col;          // storage x
    float2* base = freq + ((size_t)b << 16) + x;

    float2 v0 = base[(size_t)j * NBOX];
    float2 v1 = base[(size_t)(j + 128) * NBOX];
    s_re[col][j] = v0.x;        s_im[col][j] = v0.y;
    s_re[col][j + 128] = v1.x;  s_im[col][j + 128] = v1.y;
    __syncthreads();

    fft_dif_soa(s_re[col], s_im[col], tw, j);

    const float* cb = ctf + ((size_t)b << 16) + rev8(x);
    float c0 = cb[rev8(j) * NBOX];
    float c1 = cb[rev8(j + 128) * NBOX];
    s_re[col][j] *= c0;        s_im[col][j] *= c0;
    s_re[col][j + 128] *= c1;  s_im[col][j + 128] *= c1;
    __syncthreads();

    fft_dit_soa(s_re[col], s_im[col], tw, j);

    const float inv = 1.0f / 256.0f;
    base[(size_t)j * NBOX]         = make_float2(s_re[col][j] * inv, s_im[col][j] * inv);
    base[(size_t)(j + 128) * NBOX] = make_float2(s_re[col][j + 128] * inv, s_im[col][j + 128] * inv);
}

// ---------------- Pass C: inverse row FFT -> real output ----------------
__global__ __launch_bounds__(256) void fft_rows_inv_kernel(const float2* __restrict__ freq,
                                                           float* __restrict__ out)
{
    __shared__ float2 s[2][NBOX];
    __shared__ float2 tw[128];
    int tid = threadIdx.x;
    int tx = tid & 127, ty = tid >> 7;
    init_tw(tw, tid);
    int row = blockIdx.x * 2 + ty;
    const float2* rp = freq + (size_t)row * NBOX;
    s[ty][tx]       = rp[tx];
    s[ty][tx + 128] = rp[tx + 128];
    __syncthreads();
    fft_dit_t(s[ty], tw, tx);
    const float inv = 1.0f / 256.0f;
    out[(size_t)row * NBOX + tx]       = s[ty][tx].x * inv;
    out[(size_t)row * NBOX + tx + 128] = s[ty][tx + 128].x * inv;
}

extern "C" void kernel_launch(void* const* d_in, const int* in_sizes, int n_in,
                              void* d_out, int out_size, void* d_ws, size_t ws_size,
                              hipStream_t stream)
{
    (void)in_sizes; (void)n_in; (void)out_size;
    const float* z_x     = (const float*)d_in[0];
    const float* z_y     = (const float*)d_in[1];
    const float* z_z     = (const float*)d_in[2];
    const float* Zb      = (const float*)d_in[3];
    const float* coords  = (const float*)d_in[4];
    const float* weights = (const float*)d_in[5];
    const float* R       = (const float*)d_in[6];
    const float* shifts  = (const float*)d_in[7];
    const float* ctf     = (const float*)d_in[8];
    float* out = (float*)d_out;

    const size_t NELEM = (size_t)NIMG * NBOX * NBOX;           // 2,097,152
    const size_t NPAIR = (size_t)NIMG * NPTS;                  // 9.6 M
    float*  img   = (float*)d_ws;                              // 8 MB
    float2* freq  = (float2*)(img + NELEM);                    // 16 MB
    float2* pairs = freq + NELEM;                              // 76.8 MB
    float2* uvbuf = pairs + NPAIR;                             // 16 KB
    float4* hdrbuf = (float4*)(uvbuf + NIMG * NL);             // 1 KB
    const size_t required = NELEM * 4 + NELEM * 8 + NPAIR * 8
                          + NIMG * NL * 8 + NIMG * 2 * 16;

    if (ws_size >= required) {
        uvprep_kernel<<<1, 256, 0, stream>>>(z_x, z_y, z_z, R, shifts, uvbuf, hdrbuf);
        project2_kernel<<<(NPTS + 511) / 512, 256, 0, stream>>>(
            Zb, coords, (const float4*)uvbuf, hdrbuf, pairs);
        splat2_kernel<<<NIMG * BANDS, 512, 0, stream>>>(pairs, weights, img);
    } else {
        zero_kernel<<<(int)(NELEM / 4 + 255) / 256, 256, 0, stream>>>((float4*)img, (int)(NELEM / 4));
        splat_kernel<<<(NPTS + 255) / 256, 256, 0, stream>>>(z_x, z_y, z_z, Zb, coords,
                                                             weights, R, shifts, img);
    }

    // fused blur + row FFT
    fft_rows_fwd_blur_kernel<<<NIMG * NBOX / 2, 256, 0, stream>>>(img, freq);
    // 8-column fused col-FFT * ctf * inv-col-FFT
    fft_cols_ctf8_kernel<<<NIMG * 32, 1024, 0, stream>>>(freq, ctf);
    // inverse row FFT -> real out
    fft_rows_inv_kernel<<<NIMG * NBOX / 2, 256, 0, stream>>>(freq, out);
}

// Round 12
// 295.704 us; speedup vs baseline: 2.3250x; 2.3250x over previous
//
#include <hip/hip_runtime.h>
#include <hip/hip_bf16.h>

#define NIMG 32
#define NPTS 300000
#define NL   64
#define NBOX 256

#define BANDS  8
#define BROWS  32          // NBOX / BANDS
#define CHUNKS 2
#define CHPTS  (NPTS / CHUNKS)   // 150000
#define NGROUP (NIMG * CHUNKS)   // 64

#define QSCALE 1048576.0f        // 2^20 fixed-point scale
#define QINV   (1.0f / 1048576.0f)

typedef float v2f __attribute__((ext_vector_type(2)));

__device__ __forceinline__ int rev8(int x) { return (int)(__brev((unsigned)x) >> 24); }

// ---------------- zero fill ----------------
__global__ __launch_bounds__(256) void zero_kernel(float4* p, int n4) {
    int i = blockIdx.x * 256 + threadIdx.x;
    if (i < n4) p[i] = make_float4(0.f, 0.f, 0.f, 0.f);
}

// ---------------- Pass 1: deformation + rotate + shift -> interleaved (px,py) ----------------
__global__ __launch_bounds__(256) void project_kernel(
    const float* __restrict__ z_x, const float* __restrict__ z_y,
    const float* __restrict__ z_z, const float* __restrict__ Zb,
    const float* __restrict__ coords,
    const float* __restrict__ R, const float* __restrict__ shifts,
    float2* __restrict__ pairs)
{
    __shared__ float s_z[3][NIMG][NL];   // 24 KB
    __shared__ float s_R[NIMG][9];
    __shared__ float s_sh[NIMG][2];

    int tid = threadIdx.x;
    for (int i = tid; i < NIMG * NL; i += 256) {
        (&s_z[0][0][0])[i] = z_x[i];
        (&s_z[1][0][0])[i] = z_y[i];
        (&s_z[2][0][0])[i] = z_z[i];
    }
    for (int i = tid; i < NIMG * 9; i += 256) (&s_R[0][0])[i] = R[i];
    if (tid < NIMG * 2) (&s_sh[0][0])[tid] = shifts[tid];
    __syncthreads();

    int p = blockIdx.x * 256 + tid;
    if (p >= NPTS) return;

    v2f zr[32];
    {
        const float4* Zr4 = (const float4*)(Zb + (size_t)p * NL);
        float4 tmp[16];
        #pragma unroll
        for (int i = 0; i < 16; ++i) tmp[i] = Zr4[i];
        const v2f* t2 = (const v2f*)tmp;
        #pragma unroll
        for (int i = 0; i < 32; ++i) zr[i] = t2[i];
    }

    float cx0 = coords[3 * p + 0];
    float cy0 = coords[3 * p + 1];
    float cz0 = coords[3 * p + 2];

    for (int b = 0; b < NIMG; ++b) {
        const v2f* zx2 = (const v2f*)s_z[0][b];
        const v2f* zy2 = (const v2f*)s_z[1][b];
        const v2f* zz2 = (const v2f*)s_z[2][b];
        v2f ax = {0.f, 0.f}, ay = {0.f, 0.f}, az = {0.f, 0.f};
        #pragma unroll
        for (int i = 0; i < 32; ++i) {
            ax += zx2[i] * zr[i];
            ay += zy2[i] * zr[i];
            az += zz2[i] * zr[i];
        }
        float cx = cx0 + ax.x + ax.y;
        float cy = cy0 + ay.x + ay.y;
        float cz = cz0 + az.x + az.y;
        const float* Rb = s_R[b];
        float px = Rb[0] * cx + Rb[1] * cy + Rb[2] * cz + s_sh[b][0] + 128.0f;
        float py = Rb[3] * cx + Rb[4] * cy + Rb[5] * cz + s_sh[b][1] + 128.0f;
        pairs[(size_t)b * NPTS + p] = make_float2(px, py);
    }
}

// ---------------- Pass 2: band splat, packed u64 fixed-point LDS atomics ----------------
// tA64[r][j] covers x = 2j (lo), 2j+1 (hi), j in [0,128)
// tB64[r][j] covers x = 2j-1 (lo), 2j (hi), j in [0,129)  (shifted view)
// even xi0: tA64[r][xi0>>1] += (w00 lo, w10 hi)
// odd  xi0: tB64[r][(xi0+1)>>1] += (w00 lo, w10 hi)
// Per-pixel sums ~20 * 2^20 << 2^32 -> no cross-field carry; error ~1e-5.
__global__ __launch_bounds__(256) void splat2_kernel(
    const float2* __restrict__ pairs, const float* __restrict__ weights,
    float* __restrict__ img)
{
    __shared__ unsigned long long tA64[BROWS * 128];   // 32 KB
    __shared__ unsigned long long tB64[BROWS * 129];   // 33 KB
    int tid = threadIdx.x;
    int id = blockIdx.x;
    int band = id >> 6;           // 0..7
    int g    = id & 63;           // group = b*CHUNKS + c
    int b = g >> 1, c = g & 1;

    for (int i = tid; i < BROWS * 128; i += 256) tA64[i] = 0ULL;
    for (int i = tid; i < BROWS * 129; i += 256) tB64[i] = 0ULL;
    __syncthreads();

    const int y_lo = band * BROWS;
    const float2* pp = pairs + (size_t)b * NPTS + (size_t)c * CHPTS;
    const float*  wp = weights + (size_t)c * CHPTS;

    for (int i = 4 * tid; i < CHPTS; i += 1024) {
        float4 q0 = *(const float4*)(pp + i);       // points i, i+1
        float4 q1 = *(const float4*)(pp + i + 2);   // points i+2, i+3
        float4 wv = *(const float4*)(wp + i);
        float pxa[4] = {q0.x, q0.z, q1.x, q1.z};
        float pya[4] = {q0.y, q0.w, q1.y, q1.w};
        float wa[4]  = {wv.x, wv.y, wv.z, wv.w};
        #pragma unroll
        for (int k = 0; k < 4; ++k) {
            float px = pxa[k], py = pya[k], w = wa[k];
            float x0 = floorf(px), y0 = floorf(py);
            float fx = px - x0, fy = py - y0;
            int xi0 = min(max((int)x0, 0), NBOX - 1);
            int yi0 = min(max((int)y0, 0), NBOX - 1);
            int yi1 = min(yi0 + 1, NBOX - 1);
            float w00 = w * (1.f - fx) * (1.f - fy);
            float w10 = w * fx * (1.f - fy);
            float w01 = w * (1.f - fx) * fy;
            float w11 = w * fx * fy;
            if (xi0 == NBOX - 1) {        // xi1 clamps onto xi0: fold pair
                w00 += w10; w10 = 0.f;
                w01 += w11; w11 = 0.f;
            }
            unsigned l0 = (unsigned)(w00 * QSCALE + 0.5f);
            unsigned h0 = (unsigned)(w10 * QSCALE + 0.5f);
            unsigned l1 = (unsigned)(w01 * QSCALE + 0.5f);
            unsigned h1 = (unsigned)(w11 * QSCALE + 0.5f);
            unsigned long long v0 = (unsigned long long)l0 | ((unsigned long long)h0 << 32);
            unsigned long long v1 = (unsigned long long)l1 | ((unsigned long long)h1 << 32);
            int r0 = yi0 - y_lo, r1 = yi1 - y_lo;
            int ra = r0 & (BROWS - 1), rb = r1 & (BROWS - 1);
            bool odd = (xi0 & 1);
            unsigned long long* q0p = odd ? &tB64[ra * 129 + ((xi0 + 1) >> 1)]
                                          : &tA64[ra * 128 + (xi0 >> 1)];
            unsigned long long* q1p = odd ? &tB64[rb * 129 + ((xi0 + 1) >> 1)]
                                          : &tA64[rb * 128 + (xi0 >> 1)];
            if ((unsigned)r0 < BROWS) atomicAdd(q0p, v0);
            if ((unsigned)r1 < BROWS) atomicAdd(q1p, v1);
        }
    }
    __syncthreads();
    // flush: pixel x gets tA field (x&1) of pair x>>1, tB field from shifted view
    float* ib = img + (size_t)b * NBOX * NBOX + (size_t)y_lo * NBOX;
    for (int i = tid; i < BROWS * NBOX; i += 256) {
        int r = i >> 8, x = i & 255;
        unsigned long long a = tA64[r * 128 + (x >> 1)];
        unsigned long long bb = tB64[r * 129 + ((x + 1) >> 1)];
        unsigned fa = (x & 1) ? (unsigned)(a >> 32) : (unsigned)a;
        unsigned fb = (x & 1) ? (unsigned)bb : (unsigned)(bb >> 32);
        float val = ((float)fa + (float)fb) * QINV;
        unsafeAtomicAdd(ib + i, val);
    }
}

// ---------------- fallback: fused splat with global atomics (small ws) ----------------
__global__ __launch_bounds__(256) void splat_kernel(
    const float* __restrict__ z_x, const float* __restrict__ z_y,
    const float* __restrict__ z_z, const float* __restrict__ Zb,
    const float* __restrict__ coords, const float* __restrict__ weights,
    const float* __restrict__ R, const float* __restrict__ shifts,
    float* __restrict__ img)
{
    __shared__ float s_z[3][NIMG][NL];
    __shared__ float s_R[NIMG][9];
    __shared__ float s_sh[NIMG][2];

    int tid = threadIdx.x;
    for (int i = tid; i < NIMG * NL; i += 256) {
        (&s_z[0][0][0])[i] = z_x[i];
        (&s_z[1][0][0])[i] = z_y[i];
        (&s_z[2][0][0])[i] = z_z[i];
    }
    for (int i = tid; i < NIMG * 9; i += 256) (&s_R[0][0])[i] = R[i];
    if (tid < NIMG * 2) (&s_sh[0][0])[tid] = shifts[tid];
    __syncthreads();

    int p = blockIdx.x * 256 + tid;
    if (p >= NPTS) return;

    float4 zr[16];
    const float4* Zr4 = (const float4*)(Zb + (size_t)p * NL);
    #pragma unroll
    for (int i = 0; i < 16; ++i) zr[i] = Zr4[i];

    float cx0 = coords[3 * p + 0];
    float cy0 = coords[3 * p + 1];
    float cz0 = coords[3 * p + 2];
    float w   = weights[p];

    for (int b = 0; b < NIMG; ++b) {
        const float4* zx4 = (const float4*)s_z[0][b];
        const float4* zy4 = (const float4*)s_z[1][b];
        const float4* zz4 = (const float4*)s_z[2][b];
        float dx = 0.f, dy = 0.f, dz = 0.f;
        #pragma unroll
        for (int i = 0; i < 16; ++i) {
            float4 a = zx4[i];
            dx += a.x * zr[i].x + a.y * zr[i].y + a.z * zr[i].z + a.w * zr[i].w;
            float4 bb = zy4[i];
            dy += bb.x * zr[i].x + bb.y * zr[i].y + bb.z * zr[i].z + bb.w * zr[i].w;
            float4 c = zz4[i];
            dz += c.x * zr[i].x + c.y * zr[i].y + c.z * zr[i].z + c.w * zr[i].w;
        }
        float cx = cx0 + dx, cy = cy0 + dy, cz = cz0 + dz;
        const float* Rb = s_R[b];
        float px = Rb[0] * cx + Rb[1] * cy + Rb[2] * cz + s_sh[b][0] + 128.0f;
        float py = Rb[3] * cx + Rb[4] * cy + Rb[5] * cz + s_sh[b][1] + 128.0f;

        float x0 = floorf(px), y0 = floorf(py);
        float fx = px - x0, fy = py - y0;
        int xi0 = min(max((int)x0, 0), NBOX - 1);
        int yi0 = min(max((int)y0, 0), NBOX - 1);
        int xi1 = min(xi0 + 1, NBOX - 1);
        int yi1 = min(yi0 + 1, NBOX - 1);

        float* ib = img + (size_t)b * NBOX * NBOX;
        unsafeAtomicAdd(ib + yi0 * NBOX + xi0, w * (1.f - fx) * (1.f - fy));
        unsafeAtomicAdd(ib + yi0 * NBOX + xi1, w * fx * (1.f - fy));
        unsafeAtomicAdd(ib + yi1 * NBOX + xi0, w * (1.f - fx) * fy);
        unsafeAtomicAdd(ib + yi1 * NBOX + xi1, w * fx * fy);
    }
}

// ---------------- 256-pt FFT helpers (AOS float2, LDS twiddle) ----------------
__device__ __forceinline__ void fft_dif_t(float2* s, const float2* tw, int t) {
    #pragma unroll
    for (int st = 7; st >= 0; --st) {
        int half = 1 << st;
        int j  = t & (half - 1);
        int i1 = ((t >> st) << (st + 1)) + j;
        int i2 = i1 + half;
        float2 a = s[i1], b = s[i2];
        float2 w = tw[j << (7 - st)];
        float dxr = a.x - b.x, dxi = a.y - b.y;
        s[i1] = make_float2(a.x + b.x, a.y + b.y);
        s[i2] = make_float2(w.x * dxr - w.y * dxi, w.x * dxi + w.y * dxr);
        __syncthreads();
    }
}

__device__ __forceinline__ void fft_dit_t(float2* s, const float2* tw, int t) {
    #pragma unroll
    for (int st = 0; st < 8; ++st) {
        int half = 1 << st;
        int j  = t & (half - 1);
        int i1 = ((t >> st) << (st + 1)) + j;
        int i2 = i1 + half;
        float2 a = s[i1], b = s[i2];
        float2 w = tw[j << (7 - st)];
        float cs = w.x, sn = -w.y;
        float tr = cs * b.x - sn * b.y;
        float ti = cs * b.y + sn * b.x;
        s[i1] = make_float2(a.x + tr, a.y + ti);
        s[i2] = make_float2(a.x - tr, a.y - ti);
        __syncthreads();
    }
}

// ---------------- SOA FFT helpers (8-col kernel) ----------------
__device__ __forceinline__ void fft_dif_soa(float* re, float* im, const float2* tw, int t) {
    #pragma unroll
    for (int st = 7; st >= 0; --st) {
        int half = 1 << st;
        int j  = t & (half - 1);
        int i1 = ((t >> st) << (st + 1)) + j;
        int i2 = i1 + half;
        float ar = re[i1], ai = im[i1], br = re[i2], bi = im[i2];
        float2 w = tw[j << (7 - st)];
        float dr = ar - br, di = ai - bi;
        re[i1] = ar + br;  im[i1] = ai + bi;
        re[i2] = w.x * dr - w.y * di;
        im[i2] = w.x * di + w.y * dr;
        __syncthreads();
    }
}

__device__ __forceinline__ void fft_dit_soa(float* re, float* im, const float2* tw, int t) {
    #pragma unroll
    for (int st = 0; st < 8; ++st) {
        int half = 1 << st;
        int j  = t & (half - 1);
        int i1 = ((t >> st) << (st + 1)) + j;
        int i2 = i1 + half;
        float ar = re[i1], ai = im[i1], br = re[i2], bi = im[i2];
        float2 w = tw[j << (7 - st)];
        float cs = w.x, sn = -w.y;
        float tr = cs * br - sn * bi;
        float ti = cs * bi + sn * br;
        re[i1] = ar + tr;  im[i1] = ai + ti;
        re[i2] = ar - tr;  im[i2] = ai - ti;
        __syncthreads();
    }
}

__device__ __forceinline__ void init_tw(float2* tw, int tid) {
    if (tid < 128) {
        float sn, cs;
        sincosf(-6.283185307179586f * (float)tid * (1.0f / 256.0f), &sn, &cs);
        tw[tid] = make_float2(cs, sn);
    }
}

// ---------------- Pass A: fused 5x5 blur + forward row FFT ----------------
__global__ __launch_bounds__(256) void fft_rows_fwd_blur_kernel(const float* __restrict__ img,
                                                                float2* __restrict__ freq)
{
    __shared__ float2 s[2][NBOX];
    __shared__ float  sb[2][NBOX];
    __shared__ float2 tw[128];
    int tid = threadIdx.x;
    int tx = tid & 127, ty = tid >> 7;
    init_tw(tw, tid);
    int row = blockIdx.x * 2 + ty;     // 0 .. B*N-1
    int b = row >> 8, y = row & (NBOX - 1);
    const float* ib = img + ((size_t)b << 16);
    const float gw[5] = {0.0544886845f, 0.2442013420f, 0.4026199469f,
                         0.2442013420f, 0.0544886845f};
    float acc0 = 0.f, acc1 = 0.f;
    #pragma unroll
    for (int dy = -2; dy <= 2; ++dy) {
        int yy = y + dy;
        if ((unsigned)yy < (unsigned)NBOX) {
            const float* rp = ib + yy * NBOX;
            acc0 += gw[dy + 2] * rp[tx];
            acc1 += gw[dy + 2] * rp[tx + 128];
        }
    }
    sb[ty][tx] = acc0;  sb[ty][tx + 128] = acc1;
    __syncthreads();
    float r0 = 0.f, r1 = 0.f;
    #pragma unroll
    for (int dx = -2; dx <= 2; ++dx) {
        int x0 = tx + dx, x1 = tx + 128 + dx;
        if ((unsigned)x0 < (unsigned)NBOX) r0 += gw[dx + 2] * sb[ty][x0];
        if ((unsigned)x1 < (unsigned)NBOX) r1 += gw[dx + 2] * sb[ty][x1];
    }
    s[ty][tx]       = make_float2(r0, 0.f);
    s[ty][tx + 128] = make_float2(r1, 0.f);
    __syncthreads();
    fft_dif_t(s[ty], tw, tx);
    float2* op = freq + (size_t)row * NBOX;
    op[tx]       = s[ty][tx];
    op[tx + 128] = s[ty][tx + 128];
}

// ---------------- Pass B: 8-column fused fwd-FFT * ctf * inv-FFT ----------------
__global__ __launch_bounds__(1024) void fft_cols_ctf8_kernel(float2* __restrict__ freq,
                                                             const float* __restrict__ ctf)
{
    __shared__ float  s_re[8][257];
    __shared__ float  s_im[8][257];
    __shared__ float2 tw[128];
    int tid = threadIdx.x;
    init_tw(tw, tid);
    int col = tid & 7, j = tid >> 3;          // j in 0..127
    int blk = blockIdx.x;
    int b = blk >> 5;
    int x = ((blk & 31) << 3) + col;          // storage x
    float2* base = freq + ((size_t)b << 16) + x;

    float2 v0 = base[(size_t)j * NBOX];
    float2 v1 = base[(size_t)(j + 128) * NBOX];
    s_re[col][j] = v0.x;        s_im[col][j] = v0.y;
    s_re[col][j + 128] = v1.x;  s_im[col][j + 128] = v1.y;
    __syncthreads();

    fft_dif_soa(s_re[col], s_im[col], tw, j);

    const float* cb = ctf + ((size_t)b << 16) + rev8(x);
    float c0 = cb[rev8(j) * NBOX];
    float c1 = cb[rev8(j + 128) * NBOX];
    s_re[col][j] *= c0;        s_im[col][j] *= c0;
    s_re[col][j + 128] *= c1;  s_im[col][j + 128] *= c1;
    __syncthreads();

    fft_dit_soa(s_re[col], s_im[col], tw, j);

    const float inv = 1.0f / 256.0f;
    base[(size_t)j * NBOX]         = make_float2(s_re[col][j] * inv, s_im[col][j] * inv);
    base[(size_t)(j + 128) * NBOX] = make_float2(s_re[col][j + 128] * inv, s_im[col][j + 128] * inv);
}

// ---------------- Pass C: inverse row FFT -> real output ----------------
__global__ __launch_bounds__(256) void fft_rows_inv_kernel(const float2* __restrict__ freq,
                                                           float* __restrict__ out)
{
    __shared__ float2 s[2][NBOX];
    __shared__ float2 tw[128];
    int tid = threadIdx.x;
    int tx = tid & 127, ty = tid >> 7;
    init_tw(tw, tid);
    int row = blockIdx.x * 2 + ty;
    const float2* rp = freq + (size_t)row * NBOX;
    s[ty][tx]       = rp[tx];
    s[ty][tx + 128] = rp[tx + 128];
    __syncthreads();
    fft_dit_t(s[ty], tw, tx);
    const float inv = 1.0f / 256.0f;
    out[(size_t)row * NBOX + tx]       = s[ty][tx].x * inv;
    out[(size_t)row * NBOX + tx + 128] = s[ty][tx + 128].x * inv;
}

extern "C" void kernel_launch(void* const* d_in, const int* in_sizes, int n_in,
                              void* d_out, int out_size, void* d_ws, size_t ws_size,
                              hipStream_t stream)
{
    (void)in_sizes; (void)n_in; (void)out_size;
    const float* z_x     = (const float*)d_in[0];
    const float* z_y     = (const float*)d_in[1];
    const float* z_z     = (const float*)d_in[2];
    const float* Zb      = (const float*)d_in[3];
    const float* coords  = (const float*)d_in[4];
    const float* weights = (const float*)d_in[5];
    const float* R       = (const float*)d_in[6];
    const float* shifts  = (const float*)d_in[7];
    const float* ctf     = (const float*)d_in[8];
    float* out = (float*)d_out;

    const size_t NELEM = (size_t)NIMG * NBOX * NBOX;           // 2,097,152
    const size_t NPAIR = (size_t)NIMG * NPTS;                  // 9.6 M
    float*  img   = (float*)d_ws;                              // 8 MB
    float2* freq  = (float2*)(img + NELEM);                    // 16 MB
    float2* pairs = freq + NELEM;                              // 76.8 MB
    const size_t required = NELEM * 4 + NELEM * 8 + NPAIR * 8;

    zero_kernel<<<(int)(NELEM / 4 + 255) / 256, 256, 0, stream>>>((float4*)img, (int)(NELEM / 4));

    if (ws_size >= required) {
        project_kernel<<<(NPTS + 255) / 256, 256, 0, stream>>>(z_x, z_y, z_z, Zb, coords,
                                                               R, shifts, pairs);
        splat2_kernel<<<NGROUP * BANDS, 256, 0, stream>>>(pairs, weights, img);
    } else {
        splat_kernel<<<(NPTS + 255) / 256, 256, 0, stream>>>(z_x, z_y, z_z, Zb, coords,
                                                             weights, R, shifts, img);
    }

    // fused blur + row FFT
    fft_rows_fwd_blur_kernel<<<NIMG * NBOX / 2, 256, 0, stream>>>(img, freq);
    // 8-column fused col-FFT * ctf * inv-col-FFT
    fft_cols_ctf8_kernel<<<NIMG * 32, 1024, 0, stream>>>(freq, ctf);
    // inverse row FFT -> real out
    fft_rows_inv_kernel<<<NIMG * NBOX / 2, 256, 0, stream>>>(freq, out);
}

// Round 13
// 279.565 us; speedup vs baseline: 2.4592x; 1.0577x over previous
//
#include <hip/hip_runtime.h>
#include <hip/hip_bf16.h>

#define NIMG 32
#define NPTS 300000
#define NL   64
#define NBOX 256

#define BANDS  8
#define BROWS  32          // NBOX / BANDS
#define CHUNKS 2
#define CHPTS  (NPTS / CHUNKS)   // 150000
#define NGROUP (NIMG * CHUNKS)   // 64

#define WQS  65535.0f            // 16-bit weight quantization scale
#define WQI  (1.0f / 65535.0f)

typedef float v2f __attribute__((ext_vector_type(2)));
typedef unsigned long long u64;

__device__ __forceinline__ int rev8(int x) { return (int)(__brev((unsigned)x) >> 24); }

// ---------------- zero fill ----------------
__global__ __launch_bounds__(256) void zero_kernel(float4* p, int n4) {
    int i = blockIdx.x * 256 + threadIdx.x;
    if (i < n4) p[i] = make_float4(0.f, 0.f, 0.f, 0.f);
}

// ---------------- Pass 1: deformation + rotate + shift -> packed splat records ----------------
// wts[b*NPTS+p] = w00q | w10q<<16 | w01q<<32 | w11q<<48  (16-bit fields, edge-folded)
// pos[b*NPTS+p] = xi0 | yi0<<8
__global__ __launch_bounds__(256) void project_kernel(
    const float* __restrict__ z_x, const float* __restrict__ z_y,
    const float* __restrict__ z_z, const float* __restrict__ Zb,
    const float* __restrict__ coords, const float* __restrict__ weights,
    const float* __restrict__ R, const float* __restrict__ shifts,
    u64* __restrict__ wts, unsigned short* __restrict__ pos)
{
    __shared__ float s_z[3][NIMG][NL];   // 24 KB
    __shared__ float s_R[NIMG][9];
    __shared__ float s_sh[NIMG][2];

    int tid = threadIdx.x;
    for (int i = tid; i < NIMG * NL; i += 256) {
        (&s_z[0][0][0])[i] = z_x[i];
        (&s_z[1][0][0])[i] = z_y[i];
        (&s_z[2][0][0])[i] = z_z[i];
    }
    for (int i = tid; i < NIMG * 9; i += 256) (&s_R[0][0])[i] = R[i];
    if (tid < NIMG * 2) (&s_sh[0][0])[tid] = shifts[tid];
    __syncthreads();

    int p = blockIdx.x * 256 + tid;
    if (p >= NPTS) return;

    v2f zr[32];
    {
        const float4* Zr4 = (const float4*)(Zb + (size_t)p * NL);
        float4 tmp[16];
        #pragma unroll
        for (int i = 0; i < 16; ++i) tmp[i] = Zr4[i];
        const v2f* t2 = (const v2f*)tmp;
        #pragma unroll
        for (int i = 0; i < 32; ++i) zr[i] = t2[i];
    }

    float cx0 = coords[3 * p + 0];
    float cy0 = coords[3 * p + 1];
    float cz0 = coords[3 * p + 2];
    float w   = weights[p];

    for (int b = 0; b < NIMG; ++b) {
        const v2f* zx2 = (const v2f*)s_z[0][b];
        const v2f* zy2 = (const v2f*)s_z[1][b];
        const v2f* zz2 = (const v2f*)s_z[2][b];
        v2f ax = {0.f, 0.f}, ay = {0.f, 0.f}, az = {0.f, 0.f};
        #pragma unroll
        for (int i = 0; i < 32; ++i) {
            ax += zx2[i] * zr[i];
            ay += zy2[i] * zr[i];
            az += zz2[i] * zr[i];
        }
        float cx = cx0 + ax.x + ax.y;
        float cy = cy0 + ay.x + ay.y;
        float cz = cz0 + az.x + az.y;
        const float* Rb = s_R[b];
        float px = Rb[0] * cx + Rb[1] * cy + Rb[2] * cz + s_sh[b][0] + 128.0f;
        float py = Rb[3] * cx + Rb[4] * cy + Rb[5] * cz + s_sh[b][1] + 128.0f;

        float x0f = floorf(px), y0f = floorf(py);
        float fx = px - x0f, fy = py - y0f;
        int xi0 = min(max((int)x0f, 0), NBOX - 1);
        int yi0 = min(max((int)y0f, 0), NBOX - 1);
        float w00 = w * (1.f - fx) * (1.f - fy);
        float w10 = w * fx * (1.f - fy);
        float w01 = w * (1.f - fx) * fy;
        float w11 = w * fx * fy;
        if (xi0 == NBOX - 1) {        // xi1 clamps onto xi0: fold pair
            w00 += w10; w10 = 0.f;
            w01 += w11; w11 = 0.f;
        }
        unsigned a  = (unsigned)(w00 * WQS + 0.5f) | ((unsigned)(w10 * WQS + 0.5f) << 16);
        unsigned bq = (unsigned)(w01 * WQS + 0.5f) | ((unsigned)(w11 * WQS + 0.5f) << 16);
        wts[(size_t)b * NPTS + p] = (u64)a | ((u64)bq << 32);
        pos[(size_t)b * NPTS + p] = (unsigned short)(xi0 | (yi0 << 8));
    }
}

// ---------------- Pass 2: band splat, packed u64 LDS atomics, precomputed records ----------------
// tA64[r][j] covers x = 2j (lo32), 2j+1 (hi32), j in [0,128)
// tB64[r][j] covers x = 2j-1 (lo32), 2j (hi32), j in [0,129)  (shifted view)
__global__ __launch_bounds__(256) void splat2_kernel(
    const u64* __restrict__ wts, const unsigned short* __restrict__ pos,
    float* __restrict__ img)
{
    __shared__ u64 tA64[BROWS * 128];   // 32 KB
    __shared__ u64 tB64[BROWS * 129];   // 33 KB
    int tid = threadIdx.x;
    int id = blockIdx.x;
    int band = id >> 6;           // 0..7
    int g    = id & 63;           // group = b*CHUNKS + c
    int b = g >> 1, c = g & 1;

    for (int i = tid; i < BROWS * 128; i += 256) tA64[i] = 0ULL;
    for (int i = tid; i < BROWS * 129; i += 256) tB64[i] = 0ULL;
    __syncthreads();

    const int y_lo = band * BROWS;
    const u64* wp = wts + (size_t)b * NPTS + (size_t)c * CHPTS;
    const unsigned short* pp = pos + (size_t)b * NPTS + (size_t)c * CHPTS;

    for (int i = 4 * tid; i < CHPTS; i += 1024) {
        ulonglong2 W01 = *(const ulonglong2*)(wp + i);       // points i, i+1
        ulonglong2 W23 = *(const ulonglong2*)(wp + i + 2);   // points i+2, i+3
        u64 P4 = *(const u64*)(pp + i);                      // 4 x u16
        u64 Wa[4] = {W01.x, W01.y, W23.x, W23.y};
        #pragma unroll
        for (int k = 0; k < 4; ++k) {
            unsigned ps = (unsigned)(P4 >> (16 * k)) & 0xFFFFu;
            int xi0 = ps & 255;
            int yi0 = ps >> 8;
            int yi1 = min(yi0 + 1, NBOX - 1);
            int r0 = yi0 - y_lo, r1 = yi1 - y_lo;
            u64 W = Wa[k];
            u64 v0 = (W & 0xFFFFULL) | ((W & 0xFFFF0000ULL) << 16);
            u64 v1 = ((W >> 32) & 0xFFFFULL) | ((W >> 48) << 32);
            int ra = r0 & (BROWS - 1), rb = r1 & (BROWS - 1);
            bool odd = (xi0 & 1);
            u64* q0p = odd ? &tB64[ra * 129 + ((xi0 + 1) >> 1)]
                           : &tA64[ra * 128 + (xi0 >> 1)];
            u64* q1p = odd ? &tB64[rb * 129 + ((xi0 + 1) >> 1)]
                           : &tA64[rb * 128 + (xi0 >> 1)];
            if ((unsigned)r0 < BROWS) atomicAdd(q0p, v0);
            if ((unsigned)r1 < BROWS) atomicAdd(q1p, v1);
        }
    }
    __syncthreads();
    // flush: pixel x gets tA field (x&1) of pair x>>1, tB field from shifted view
    float* ib = img + (size_t)b * NBOX * NBOX + (size_t)y_lo * NBOX;
    for (int i = tid; i < BROWS * NBOX; i += 256) {
        int r = i >> 8, x = i & 255;
        u64 a  = tA64[r * 128 + (x >> 1)];
        u64 bb = tB64[r * 129 + ((x + 1) >> 1)];
        unsigned fa = (x & 1) ? (unsigned)(a >> 32) : (unsigned)a;
        unsigned fb = (x & 1) ? (unsigned)bb : (unsigned)(bb >> 32);
        float val = ((float)fa + (float)fb) * WQI;
        unsafeAtomicAdd(ib + i, val);
    }
}

// ---------------- fallback: fused splat with global atomics (small ws) ----------------
__global__ __launch_bounds__(256) void splat_kernel(
    const float* __restrict__ z_x, const float* __restrict__ z_y,
    const float* __restrict__ z_z, const float* __restrict__ Zb,
    const float* __restrict__ coords, const float* __restrict__ weights,
    const float* __restrict__ R, const float* __restrict__ shifts,
    float* __restrict__ img)
{
    __shared__ float s_z[3][NIMG][NL];
    __shared__ float s_R[NIMG][9];
    __shared__ float s_sh[NIMG][2];

    int tid = threadIdx.x;
    for (int i = tid; i < NIMG * NL; i += 256) {
        (&s_z[0][0][0])[i] = z_x[i];
        (&s_z[1][0][0])[i] = z_y[i];
        (&s_z[2][0][0])[i] = z_z[i];
    }
    for (int i = tid; i < NIMG * 9; i += 256) (&s_R[0][0])[i] = R[i];
    if (tid < NIMG * 2) (&s_sh[0][0])[tid] = shifts[tid];
    __syncthreads();

    int p = blockIdx.x * 256 + tid;
    if (p >= NPTS) return;

    float4 zr[16];
    const float4* Zr4 = (const float4*)(Zb + (size_t)p * NL);
    #pragma unroll
    for (int i = 0; i < 16; ++i) zr[i] = Zr4[i];

    float cx0 = coords[3 * p + 0];
    float cy0 = coords[3 * p + 1];
    float cz0 = coords[3 * p + 2];
    float w   = weights[p];

    for (int b = 0; b < NIMG; ++b) {
        const float4* zx4 = (const float4*)s_z[0][b];
        const float4* zy4 = (const float4*)s_z[1][b];
        const float4* zz4 = (const float4*)s_z[2][b];
        float dx = 0.f, dy = 0.f, dz = 0.f;
        #pragma unroll
        for (int i = 0; i < 16; ++i) {
            float4 a = zx4[i];
            dx += a.x * zr[i].x + a.y * zr[i].y + a.z * zr[i].z + a.w * zr[i].w;
            float4 bb = zy4[i];
            dy += bb.x * zr[i].x + bb.y * zr[i].y + bb.z * zr[i].z + bb.w * zr[i].w;
            float4 c = zz4[i];
            dz += c.x * zr[i].x + c.y * zr[i].y + c.z * zr[i].z + c.w * zr[i].w;
        }
        float cx = cx0 + dx, cy = cy0 + dy, cz = cz0 + dz;
        const float* Rb = s_R[b];
        float px = Rb[0] * cx + Rb[1] * cy + Rb[2] * cz + s_sh[b][0] + 128.0f;
        float py = Rb[3] * cx + Rb[4] * cy + Rb[5] * cz + s_sh[b][1] + 128.0f;

        float x0 = floorf(px), y0 = floorf(py);
        float fx = px - x0, fy = py - y0;
        int xi0 = min(max((int)x0, 0), NBOX - 1);
        int yi0 = min(max((int)y0, 0), NBOX - 1);
        int xi1 = min(xi0 + 1, NBOX - 1);
        int yi1 = min(yi0 + 1, NBOX - 1);

        float* ib = img + (size_t)b * NBOX * NBOX;
        unsafeAtomicAdd(ib + yi0 * NBOX + xi0, w * (1.f - fx) * (1.f - fy));
        unsafeAtomicAdd(ib + yi0 * NBOX + xi1, w * fx * (1.f - fy));
        unsafeAtomicAdd(ib + yi1 * NBOX + xi0, w * (1.f - fx) * fy);
        unsafeAtomicAdd(ib + yi1 * NBOX + xi1, w * fx * fy);
    }
}

// ---------------- 256-pt FFT helpers (AOS float2, LDS twiddle) ----------------
__device__ __forceinline__ void fft_dif_t(float2* s, const float2* tw, int t) {
    #pragma unroll
    for (int st = 7; st >= 0; --st) {
        int half = 1 << st;
        int j  = t & (half - 1);
        int i1 = ((t >> st) << (st + 1)) + j;
        int i2 = i1 + half;
        float2 a = s[i1], b = s[i2];
        float2 w = tw[j << (7 - st)];
        float dxr = a.x - b.x, dxi = a.y - b.y;
        s[i1] = make_float2(a.x + b.x, a.y + b.y);
        s[i2] = make_float2(w.x * dxr - w.y * dxi, w.x * dxi + w.y * dxr);
        __syncthreads();
    }
}

__device__ __forceinline__ void fft_dit_t(float2* s, const float2* tw, int t) {
    #pragma unroll
    for (int st = 0; st < 8; ++st) {
        int half = 1 << st;
        int j  = t & (half - 1);
        int i1 = ((t >> st) << (st + 1)) + j;
        int i2 = i1 + half;
        float2 a = s[i1], b = s[i2];
        float2 w = tw[j << (7 - st)];
        float cs = w.x, sn = -w.y;
        float tr = cs * b.x - sn * b.y;
        float ti = cs * b.y + sn * b.x;
        s[i1] = make_float2(a.x + tr, a.y + ti);
        s[i2] = make_float2(a.x - tr, a.y - ti);
        __syncthreads();
    }
}

// ---------------- SOA FFT helpers (8-col kernel) ----------------
__device__ __forceinline__ void fft_dif_soa(float* re, float* im, const float2* tw, int t) {
    #pragma unroll
    for (int st = 7; st >= 0; --st) {
        int half = 1 << st;
        int j  = t & (half - 1);
        int i1 = ((t >> st) << (st + 1)) + j;
        int i2 = i1 + half;
        float ar = re[i1], ai = im[i1], br = re[i2], bi = im[i2];
        float2 w = tw[j << (7 - st)];
        float dr = ar - br, di = ai - bi;
        re[i1] = ar + br;  im[i1] = ai + bi;
        re[i2] = w.x * dr - w.y * di;
        im[i2] = w.x * di + w.y * dr;
        __syncthreads();
    }
}

__device__ __forceinline__ void fft_dit_soa(float* re, float* im, const float2* tw, int t) {
    #pragma unroll
    for (int st = 0; st < 8; ++st) {
        int half = 1 << st;
        int j  = t & (half - 1);
        int i1 = ((t >> st) << (st + 1)) + j;
        int i2 = i1 + half;
        float ar = re[i1], ai = im[i1], br = re[i2], bi = im[i2];
        float2 w = tw[j << (7 - st)];
        float cs = w.x, sn = -w.y;
        float tr = cs * br - sn * bi;
        float ti = cs * bi + sn * br;
        re[i1] = ar + tr;  im[i1] = ai + ti;
        re[i2] = ar - tr;  im[i2] = ai - ti;
        __syncthreads();
    }
}

__device__ __forceinline__ void init_tw(float2* tw, int tid) {
    if (tid < 128) {
        float sn, cs;
        sincosf(-6.283185307179586f * (float)tid * (1.0f / 256.0f), &sn, &cs);
        tw[tid] = make_float2(cs, sn);
    }
}

// ---------------- Pass A: fused 5x5 blur + forward row FFT ----------------
__global__ __launch_bounds__(256) void fft_rows_fwd_blur_kernel(const float* __restrict__ img,
                                                                float2* __restrict__ freq)
{
    __shared__ float2 s[2][NBOX];
    __shared__ float  sb[2][NBOX];
    __shared__ float2 tw[128];
    int tid = threadIdx.x;
    int tx = tid & 127, ty = tid >> 7;
    init_tw(tw, tid);
    int row = blockIdx.x * 2 + ty;     // 0 .. B*N-1
    int b = row >> 8, y = row & (NBOX - 1);
    const float* ib = img + ((size_t)b << 16);
    const float gw[5] = {0.0544886845f, 0.2442013420f, 0.4026199469f,
                         0.2442013420f, 0.0544886845f};
    float acc0 = 0.f, acc1 = 0.f;
    #pragma unroll
    for (int dy = -2; dy <= 2; ++dy) {
        int yy = y + dy;
        if ((unsigned)yy < (unsigned)NBOX) {
            const float* rp = ib + yy * NBOX;
            acc0 += gw[dy + 2] * rp[tx];
            acc1 += gw[dy + 2] * rp[tx + 128];
        }
    }
    sb[ty][tx] = acc0;  sb[ty][tx + 128] = acc1;
    __syncthreads();
    float r0 = 0.f, r1 = 0.f;
    #pragma unroll
    for (int dx = -2; dx <= 2; ++dx) {
        int x0 = tx + dx, x1 = tx + 128 + dx;
        if ((unsigned)x0 < (unsigned)NBOX) r0 += gw[dx + 2] * sb[ty][x0];
        if ((unsigned)x1 < (unsigned)NBOX) r1 += gw[dx + 2] * sb[ty][x1];
    }
    s[ty][tx]       = make_float2(r0, 0.f);
    s[ty][tx + 128] = make_float2(r1, 0.f);
    __syncthreads();
    fft_dif_t(s[ty], tw, tx);
    float2* op = freq + (size_t)row * NBOX;
    op[tx]       = s[ty][tx];
    op[tx + 128] = s[ty][tx + 128];
}

// ---------------- Pass B: 8-column fused fwd-FFT * ctf * inv-FFT ----------------
__global__ __launch_bounds__(1024) void fft_cols_ctf8_kernel(float2* __restrict__ freq,
                                                             const float* __restrict__ ctf)
{
    __shared__ float  s_re[8][257];
    __shared__ float  s_im[8][257];
    __shared__ float2 tw[128];
    int tid = threadIdx.x;
    init_tw(tw, tid);
    int col = tid & 7, j = tid >> 3;          // j in 0..127
    int blk = blockIdx.x;
    int b = blk >> 5;
    int x = ((blk & 31) << 3) + col;          // storage x
    float2* base = freq + ((size_t)b << 16) + x;

    float2 v0 = base[(size_t)j * NBOX];
    float2 v1 = base[(size_t)(j + 128) * NBOX];
    s_re[col][j] = v0.x;        s_im[col][j] = v0.y;
    s_re[col][j + 128] = v1.x;  s_im[col][j + 128] = v1.y;
    __syncthreads();

    fft_dif_soa(s_re[col], s_im[col], tw, j);

    const float* cb = ctf + ((size_t)b << 16) + rev8(x);
    float c0 = cb[rev8(j) * NBOX];
    float c1 = cb[rev8(j + 128) * NBOX];
    s_re[col][j] *= c0;        s_im[col][j] *= c0;
    s_re[col][j + 128] *= c1;  s_im[col][j + 128] *= c1;
    __syncthreads();

    fft_dit_soa(s_re[col], s_im[col], tw, j);

    const float inv = 1.0f / 256.0f;
    base[(size_t)j * NBOX]         = make_float2(s_re[col][j] * inv, s_im[col][j] * inv);
    base[(size_t)(j + 128) * NBOX] = make_float2(s_re[col][j + 128] * inv, s_im[col][j + 128] * inv);
}

// ---------------- Pass C: inverse row FFT -> real output ----------------
__global__ __launch_bounds__(256) void fft_rows_inv_kernel(const float2* __restrict__ freq,
                                                           float* __restrict__ out)
{
    __shared__ float2 s[2][NBOX];
    __shared__ float2 tw[128];
    int tid = threadIdx.x;
    int tx = tid & 127, ty = tid >> 7;
    init_tw(tw, tid);
    int row = blockIdx.x * 2 + ty;
    const float2* rp = freq + (size_t)row * NBOX;
    s[ty][tx]       = rp[tx];
    s[ty][tx + 128] = rp[tx + 128];
    __syncthreads();
    fft_dit_t(s[ty], tw, tx);
    const float inv = 1.0f / 256.0f;
    out[(size_t)row * NBOX + tx]       = s[ty][tx].x * inv;
    out[(size_t)row * NBOX + tx + 128] = s[ty][tx + 128].x * inv;
}

extern "C" void kernel_launch(void* const* d_in, const int* in_sizes, int n_in,
                              void* d_out, int out_size, void* d_ws, size_t ws_size,
                              hipStream_t stream)
{
    (void)in_sizes; (void)n_in; (void)out_size;
    const float* z_x     = (const float*)d_in[0];
    const float* z_y     = (const float*)d_in[1];
    const float* z_z     = (const float*)d_in[2];
    const float* Zb      = (const float*)d_in[3];
    const float* coords  = (const float*)d_in[4];
    const float* weights = (const float*)d_in[5];
    const float* R       = (const float*)d_in[6];
    const float* shifts  = (const float*)d_in[7];
    const float* ctf     = (const float*)d_in[8];
    float* out = (float*)d_out;

    const size_t NELEM = (size_t)NIMG * NBOX * NBOX;           // 2,097,152
    const size_t NPAIR = (size_t)NIMG * NPTS;                  // 9.6 M
    char* base = (char*)d_ws;
    float* img = (float*)base;                                  // 8 MB
    u64*   wts = (u64*)(base + 8388608);                        // 76.8 MB
    unsigned short* pos = (unsigned short*)(base + 8388608 + 76800000);  // 19.2 MB
    // freq aliases pos (pos is dead once splat2 completes; freq written after)
    float2* freq = (float2*)(base + 8388608 + 76800000);        // 16.78 MB < 19.2 MB
    const size_t required = 8388608 + 76800000 + NPAIR * 2;     // 104.4 MB

    zero_kernel<<<(int)(NELEM / 4 + 255) / 256, 256, 0, stream>>>((float4*)img, (int)(NELEM / 4));

    if (ws_size >= required) {
        project_kernel<<<(NPTS + 255) / 256, 256, 0, stream>>>(z_x, z_y, z_z, Zb, coords,
                                                               weights, R, shifts, wts, pos);
        splat2_kernel<<<NGROUP * BANDS, 256, 0, stream>>>(wts, pos, img);
    } else {
        splat_kernel<<<(NPTS + 255) / 256, 256, 0, stream>>>(z_x, z_y, z_z, Zb, coords,
                                                             weights, R, shifts, img);
    }

    // fused blur + row FFT
    fft_rows_fwd_blur_kernel<<<NIMG * NBOX / 2, 256, 0, stream>>>(img, freq);
    // 8-column fused col-FFT * ctf * inv-col-FFT
    fft_cols_ctf8_kernel<<<NIMG * 32, 1024, 0, stream>>>(freq, ctf);
    // inverse row FFT -> real out
    fft_rows_inv_kernel<<<NIMG * NBOX / 2, 256, 0, stream>>>(freq, out);
}

// Round 14
// 260.039 us; speedup vs baseline: 2.6439x; 1.0751x over previous
//
#include <hip/hip_runtime.h>
#include <hip/hip_bf16.h>

#define NIMG 32
#define NPTS 300000
#define NL   64
#define NBOX 256

#define BANDS  8
#define BROWS  32          // NBOX / BANDS
#define CHUNKS 2
#define CHPTS  (NPTS / CHUNKS)   // 150000
#define NGROUP (NIMG * CHUNKS)   // 64

#define WQS  4095.0f             // 12-bit weight quantization scale
#define WQI  (1.0f / 4095.0f)

typedef float v2f __attribute__((ext_vector_type(2)));
typedef unsigned long long u64;

__device__ __forceinline__ int rev8(int x) { return (int)(__brev((unsigned)x) >> 24); }

// ---------------- zero fill ----------------
__global__ __launch_bounds__(256) void zero_kernel(float4* p, int n4) {
    int i = blockIdx.x * 256 + threadIdx.x;
    if (i < n4) p[i] = make_float4(0.f, 0.f, 0.f, 0.f);
}

// ---------------- P0: per-image fused coefficients ----------------
// u[b][i] = R00*z_x + R01*z_y + R02*z_z ; v[b][i] = row1 analog
// hdr[2b] = (R00,R01,R02, shx+128), hdr[2b+1] = (R10,R11,R12, shy+128)
__global__ __launch_bounds__(256) void uvprep_kernel(
    const float* __restrict__ z_x, const float* __restrict__ z_y,
    const float* __restrict__ z_z, const float* __restrict__ R,
    const float* __restrict__ shifts,
    float* __restrict__ ubuf, float* __restrict__ vbuf, float4* __restrict__ hdrbuf)
{
    int t = threadIdx.x;
    for (int e = t; e < NIMG * NL; e += 256) {
        int b = e >> 6;
        const float* Rb = R + b * 9;
        float zx = z_x[e], zy = z_y[e], zz = z_z[e];
        ubuf[e] = Rb[0] * zx + Rb[1] * zy + Rb[2] * zz;
        vbuf[e] = Rb[3] * zx + Rb[4] * zy + Rb[5] * zz;
    }
    if (t < NIMG) {
        const float* Rb = R + t * 9;
        hdrbuf[2 * t]     = make_float4(Rb[0], Rb[1], Rb[2], shifts[2 * t]     + 128.f);
        hdrbuf[2 * t + 1] = make_float4(Rb[3], Rb[4], Rb[5], shifts[2 * t + 1] + 128.f);
    }
}

// ---------------- P1: projection (2 dots/image) -> one u64 record per (image,point) ----------------
// rec = pos(16) | w00q<<16 | w10q<<28 | w01q<<40 | w11q<<52   (12-bit fields, edge-folded)
__global__ __launch_bounds__(256) void project_kernel(
    const float* __restrict__ Zb, const float* __restrict__ coords,
    const float* __restrict__ weights,
    const float* __restrict__ ubuf, const float* __restrict__ vbuf,
    const float4* __restrict__ hdrbuf,
    u64* __restrict__ recs)
{
    __shared__ float  s_u[NIMG * NL];   // 8 KB
    __shared__ float  s_v[NIMG * NL];   // 8 KB
    __shared__ float4 s_h[NIMG * 2];    // 1 KB

    int tid = threadIdx.x;
    for (int i = tid; i < NIMG * NL; i += 256) {
        s_u[i] = ubuf[i];
        s_v[i] = vbuf[i];
    }
    if (tid < NIMG * 2) s_h[tid] = hdrbuf[tid];
    __syncthreads();

    int p = blockIdx.x * 256 + tid;
    if (p >= NPTS) return;

    v2f zr[32];
    {
        const float4* Zr4 = (const float4*)(Zb + (size_t)p * NL);
        float4 tmp[16];
        #pragma unroll
        for (int i = 0; i < 16; ++i) tmp[i] = Zr4[i];
        const v2f* t2 = (const v2f*)tmp;
        #pragma unroll
        for (int i = 0; i < 32; ++i) zr[i] = t2[i];
    }

    float cx0 = coords[3 * p + 0];
    float cy0 = coords[3 * p + 1];
    float cz0 = coords[3 * p + 2];
    float w   = weights[p];

    for (int b = 0; b < NIMG; ++b) {
        float4 h0 = s_h[2 * b], h1 = s_h[2 * b + 1];
        const v2f* u2 = (const v2f*)(s_u + b * NL);
        const v2f* v2 = (const v2f*)(s_v + b * NL);
        v2f ax = {0.f, 0.f}, ay = {0.f, 0.f};
        #pragma unroll
        for (int i = 0; i < 32; ++i) {
            ax += u2[i] * zr[i];
            ay += v2[i] * zr[i];
        }
        float px = fmaf(h0.x, cx0, fmaf(h0.y, cy0, fmaf(h0.z, cz0, h0.w))) + ax.x + ax.y;
        float py = fmaf(h1.x, cx0, fmaf(h1.y, cy0, fmaf(h1.z, cz0, h1.w))) + ay.x + ay.y;

        float x0f = floorf(px), y0f = floorf(py);
        float fx = px - x0f, fy = py - y0f;
        int xi0 = min(max((int)x0f, 0), NBOX - 1);
        int yi0 = min(max((int)y0f, 0), NBOX - 1);
        float w00 = w * (1.f - fx) * (1.f - fy);
        float w10 = w * fx * (1.f - fy);
        float w01 = w * (1.f - fx) * fy;
        float w11 = w * fx * fy;
        if (xi0 == NBOX - 1) {        // xi1 clamps onto xi0: fold pair
            w00 += w10; w10 = 0.f;
            w01 += w11; w11 = 0.f;
        }
        u64 rec = (u64)(unsigned)(xi0 | (yi0 << 8))
                | ((u64)(unsigned)(w00 * WQS + 0.5f) << 16)
                | ((u64)(unsigned)(w10 * WQS + 0.5f) << 28)
                | ((u64)(unsigned)(w01 * WQS + 0.5f) << 40)
                | ((u64)(unsigned)(w11 * WQS + 0.5f) << 52);
        recs[(size_t)b * NPTS + p] = rec;
    }
}

// ---------------- P2: band splat, packed u64 LDS atomics ----------------
// tA64[r][j] covers x = 2j (lo32), 2j+1 (hi32), j in [0,128)
// tB64[r][j] covers x = 2j-1 (lo32), 2j (hi32), j in [0,129)  (shifted view)
__global__ __launch_bounds__(256) void splat2_kernel(
    const u64* __restrict__ recs, float* __restrict__ img)
{
    __shared__ u64 tA64[BROWS * 128];   // 32 KB
    __shared__ u64 tB64[BROWS * 129];   // 33 KB
    int tid = threadIdx.x;
    int id = blockIdx.x;
    int band = id >> 6;           // 0..7
    int g    = id & 63;           // group = b*CHUNKS + c
    int b = g >> 1, c = g & 1;

    for (int i = tid; i < BROWS * 128; i += 256) tA64[i] = 0ULL;
    for (int i = tid; i < BROWS * 129; i += 256) tB64[i] = 0ULL;
    __syncthreads();

    const int y_lo = band * BROWS;
    const u64* rp = recs + (size_t)b * NPTS + (size_t)c * CHPTS;

    for (int i = 4 * tid; i < CHPTS; i += 1024) {
        ulonglong2 R01 = *(const ulonglong2*)(rp + i);       // points i, i+1
        ulonglong2 R23 = *(const ulonglong2*)(rp + i + 2);   // points i+2, i+3
        u64 Ra[4] = {R01.x, R01.y, R23.x, R23.y};
        #pragma unroll
        for (int k = 0; k < 4; ++k) {
            u64 rec = Ra[k];
            unsigned ps = (unsigned)rec & 0xFFFFu;
            int xi0 = ps & 255;
            int yi0 = ps >> 8;
            int yi1 = min(yi0 + 1, NBOX - 1);
            int r0 = yi0 - y_lo, r1 = yi1 - y_lo;
            u64 v0 = ((rec >> 16) & 0xFFFULL) | (((rec >> 28) & 0xFFFULL) << 32);
            u64 v1 = ((rec >> 40) & 0xFFFULL) | (((rec >> 52) & 0xFFFULL) << 32);
            int ra = r0 & (BROWS - 1), rb = r1 & (BROWS - 1);
            bool odd = (xi0 & 1);
            u64* q0p = odd ? &tB64[ra * 129 + ((xi0 + 1) >> 1)]
                           : &tA64[ra * 128 + (xi0 >> 1)];
            u64* q1p = odd ? &tB64[rb * 129 + ((xi0 + 1) >> 1)]
                           : &tA64[rb * 128 + (xi0 >> 1)];
            if ((unsigned)r0 < BROWS) atomicAdd(q0p, v0);
            if ((unsigned)r1 < BROWS) atomicAdd(q1p, v1);
        }
    }
    __syncthreads();
    // flush: pixel x gets tA field (x&1) of pair x>>1, tB field from shifted view
    float* ib = img + (size_t)b * NBOX * NBOX + (size_t)y_lo * NBOX;
    for (int i = tid; i < BROWS * NBOX; i += 256) {
        int r = i >> 8, x = i & 255;
        u64 a  = tA64[r * 128 + (x >> 1)];
        u64 bb = tB64[r * 129 + ((x + 1) >> 1)];
        unsigned fa = (x & 1) ? (unsigned)(a >> 32) : (unsigned)a;
        unsigned fb = (x & 1) ? (unsigned)bb : (unsigned)(bb >> 32);
        float val = ((float)fa + (float)fb) * WQI;
        unsafeAtomicAdd(ib + i, val);
    }
}

// ---------------- fallback: fused splat with global atomics (small ws) ----------------
__global__ __launch_bounds__(256) void splat_kernel(
    const float* __restrict__ z_x, const float* __restrict__ z_y,
    const float* __restrict__ z_z, const float* __restrict__ Zb,
    const float* __restrict__ coords, const float* __restrict__ weights,
    const float* __restrict__ R, const float* __restrict__ shifts,
    float* __restrict__ img)
{
    __shared__ float s_z[3][NIMG][NL];
    __shared__ float s_R[NIMG][9];
    __shared__ float s_sh[NIMG][2];

    int tid = threadIdx.x;
    for (int i = tid; i < NIMG * NL; i += 256) {
        (&s_z[0][0][0])[i] = z_x[i];
        (&s_z[1][0][0])[i] = z_y[i];
        (&s_z[2][0][0])[i] = z_z[i];
    }
    for (int i = tid; i < NIMG * 9; i += 256) (&s_R[0][0])[i] = R[i];
    if (tid < NIMG * 2) (&s_sh[0][0])[tid] = shifts[tid];
    __syncthreads();

    int p = blockIdx.x * 256 + tid;
    if (p >= NPTS) return;

    float4 zr[16];
    const float4* Zr4 = (const float4*)(Zb + (size_t)p * NL);
    #pragma unroll
    for (int i = 0; i < 16; ++i) zr[i] = Zr4[i];

    float cx0 = coords[3 * p + 0];
    float cy0 = coords[3 * p + 1];
    float cz0 = coords[3 * p + 2];
    float w   = weights[p];

    for (int b = 0; b < NIMG; ++b) {
        const float4* zx4 = (const float4*)s_z[0][b];
        const float4* zy4 = (const float4*)s_z[1][b];
        const float4* zz4 = (const float4*)s_z[2][b];
        float dx = 0.f, dy = 0.f, dz = 0.f;
        #pragma unroll
        for (int i = 0; i < 16; ++i) {
            float4 a = zx4[i];
            dx += a.x * zr[i].x + a.y * zr[i].y + a.z * zr[i].z + a.w * zr[i].w;
            float4 bb = zy4[i];
            dy += bb.x * zr[i].x + bb.y * zr[i].y + bb.z * zr[i].z + bb.w * zr[i].w;
            float4 c = zz4[i];
            dz += c.x * zr[i].x + c.y * zr[i].y + c.z * zr[i].z + c.w * zr[i].w;
        }
        float cx = cx0 + dx, cy = cy0 + dy, cz = cz0 + dz;
        const float* Rb = s_R[b];
        float px = Rb[0] * cx + Rb[1] * cy + Rb[2] * cz + s_sh[b][0] + 128.0f;
        float py = Rb[3] * cx + Rb[4] * cy + Rb[5] * cz + s_sh[b][1] + 128.0f;

        float x0 = floorf(px), y0 = floorf(py);
        float fx = px - x0, fy = py - y0;
        int xi0 = min(max((int)x0, 0), NBOX - 1);
        int yi0 = min(max((int)y0, 0), NBOX - 1);
        int xi1 = min(xi0 + 1, NBOX - 1);
        int yi1 = min(yi0 + 1, NBOX - 1);

        float* ib = img + (size_t)b * NBOX * NBOX;
        unsafeAtomicAdd(ib + yi0 * NBOX + xi0, w * (1.f - fx) * (1.f - fy));
        unsafeAtomicAdd(ib + yi0 * NBOX + xi1, w * fx * (1.f - fy));
        unsafeAtomicAdd(ib + yi1 * NBOX + xi0, w * (1.f - fx) * fy);
        unsafeAtomicAdd(ib + yi1 * NBOX + xi1, w * fx * fy);
    }
}

// ---------------- 256-pt FFT helpers (AOS float2, LDS twiddle) ----------------
__device__ __forceinline__ void fft_dif_t(float2* s, const float2* tw, int t) {
    #pragma unroll
    for (int st = 7; st >= 0; --st) {
        int half = 1 << st;
        int j  = t & (half - 1);
        int i1 = ((t >> st) << (st + 1)) + j;
        int i2 = i1 + half;
        float2 a = s[i1], b = s[i2];
        float2 w = tw[j << (7 - st)];
        float dxr = a.x - b.x, dxi = a.y - b.y;
        s[i1] = make_float2(a.x + b.x, a.y + b.y);
        s[i2] = make_float2(w.x * dxr - w.y * dxi, w.x * dxi + w.y * dxr);
        __syncthreads();
    }
}

__device__ __forceinline__ void fft_dit_t(float2* s, const float2* tw, int t) {
    #pragma unroll
    for (int st = 0; st < 8; ++st) {
        int half = 1 << st;
        int j  = t & (half - 1);
        int i1 = ((t >> st) << (st + 1)) + j;
        int i2 = i1 + half;
        float2 a = s[i1], b = s[i2];
        float2 w = tw[j << (7 - st)];
        float cs = w.x, sn = -w.y;
        float tr = cs * b.x - sn * b.y;
        float ti = cs * b.y + sn * b.x;
        s[i1] = make_float2(a.x + tr, a.y + ti);
        s[i2] = make_float2(a.x - tr, a.y - ti);
        __syncthreads();
    }
}

// ---------------- SOA FFT helpers (8-col kernel) ----------------
__device__ __forceinline__ void fft_dif_soa(float* re, float* im, const float2* tw, int t) {
    #pragma unroll
    for (int st = 7; st >= 0; --st) {
        int half = 1 << st;
        int j  = t & (half - 1);
        int i1 = ((t >> st) << (st + 1)) + j;
        int i2 = i1 + half;
        float ar = re[i1], ai = im[i1], br = re[i2], bi = im[i2];
        float2 w = tw[j << (7 - st)];
        float dr = ar - br, di = ai - bi;
        re[i1] = ar + br;  im[i1] = ai + bi;
        re[i2] = w.x * dr - w.y * di;
        im[i2] = w.x * di + w.y * dr;
        __syncthreads();
    }
}

__device__ __forceinline__ void fft_dit_soa(float* re, float* im, const float2* tw, int t) {
    #pragma unroll
    for (int st = 0; st < 8; ++st) {
        int half = 1 << st;
        int j  = t & (half - 1);
        int i1 = ((t >> st) << (st + 1)) + j;
        int i2 = i1 + half;
        float ar = re[i1], ai = im[i1], br = re[i2], bi = im[i2];
        float2 w = tw[j << (7 - st)];
        float cs = w.x, sn = -w.y;
        float tr = cs * br - sn * bi;
        float ti = cs * bi + sn * br;
        re[i1] = ar + tr;  im[i1] = ai + ti;
        re[i2] = ar - tr;  im[i2] = ai - ti;
        __syncthreads();
    }
}

__device__ __forceinline__ void init_tw(float2* tw, int tid) {
    if (tid < 128) {
        float sn, cs;
        sincosf(-6.283185307179586f * (float)tid * (1.0f / 256.0f), &sn, &cs);
        tw[tid] = make_float2(cs, sn);
    }
}

// ---------------- Pass A: fused 5x5 blur + forward row FFT ----------------
__global__ __launch_bounds__(256) void fft_rows_fwd_blur_kernel(const float* __restrict__ img,
                                                                float2* __restrict__ freq)
{
    __shared__ float2 s[2][NBOX];
    __shared__ float  sb[2][NBOX];
    __shared__ float2 tw[128];
    int tid = threadIdx.x;
    int tx = tid & 127, ty = tid >> 7;
    init_tw(tw, tid);
    int row = blockIdx.x * 2 + ty;     // 0 .. B*N-1
    int b = row >> 8, y = row & (NBOX - 1);
    const float* ib = img + ((size_t)b << 16);
    const float gw[5] = {0.0544886845f, 0.2442013420f, 0.4026199469f,
                         0.2442013420f, 0.0544886845f};
    float acc0 = 0.f, acc1 = 0.f;
    #pragma unroll
    for (int dy = -2; dy <= 2; ++dy) {
        int yy = y + dy;
        if ((unsigned)yy < (unsigned)NBOX) {
            const float* rp = ib + yy * NBOX;
            acc0 += gw[dy + 2] * rp[tx];
            acc1 += gw[dy + 2] * rp[tx + 128];
        }
    }
    sb[ty][tx] = acc0;  sb[ty][tx + 128] = acc1;
    __syncthreads();
    float r0 = 0.f, r1 = 0.f;
    #pragma unroll
    for (int dx = -2; dx <= 2; ++dx) {
        int x0 = tx + dx, x1 = tx + 128 + dx;
        if ((unsigned)x0 < (unsigned)NBOX) r0 += gw[dx + 2] * sb[ty][x0];
        if ((unsigned)x1 < (unsigned)NBOX) r1 += gw[dx + 2] * sb[ty][x1];
    }
    s[ty][tx]       = make_float2(r0, 0.f);
    s[ty][tx + 128] = make_float2(r1, 0.f);
    __syncthreads();
    fft_dif_t(s[ty], tw, tx);
    float2* op = freq + (size_t)row * NBOX;
    op[tx]       = s[ty][tx];
    op[tx + 128] = s[ty][tx + 128];
}

// ---------------- Pass B: 8-column fused fwd-FFT * ctf * inv-FFT ----------------
__global__ __launch_bounds__(1024) void fft_cols_ctf8_kernel(float2* __restrict__ freq,
                                                             const float* __restrict__ ctf)
{
    __shared__ float  s_re[8][257];
    __shared__ float  s_im[8][257];
    __shared__ float2 tw[128];
    int tid = threadIdx.x;
    init_tw(tw, tid);
    int col = tid & 7, j = tid >> 3;          // j in 0..127
    int blk = blockIdx.x;
    int b = blk >> 5;
    int x = ((blk & 31) << 3) + col;          // storage x
    float2* base = freq + ((size_t)b << 16) + x;

    float2 v0 = base[(size_t)j * NBOX];
    float2 v1 = base[(size_t)(j + 128) * NBOX];
    s_re[col][j] = v0.x;        s_im[col][j] = v0.y;
    s_re[col][j + 128] = v1.x;  s_im[col][j + 128] = v1.y;
    __syncthreads();

    fft_dif_soa(s_re[col], s_im[col], tw, j);

    const float* cb = ctf + ((size_t)b << 16) + rev8(x);
    float c0 = cb[rev8(j) * NBOX];
    float c1 = cb[rev8(j + 128) * NBOX];
    s_re[col][j] *= c0;        s_im[col][j] *= c0;
    s_re[col][j + 128] *= c1;  s_im[col][j + 128] *= c1;
    __syncthreads();

    fft_dit_soa(s_re[col], s_im[col], tw, j);

    const float inv = 1.0f / 256.0f;
    base[(size_t)j * NBOX]         = make_float2(s_re[col][j] * inv, s_im[col][j] * inv);
    base[(size_t)(j + 128) * NBOX] = make_float2(s_re[col][j + 128] * inv, s_im[col][j + 128] * inv);
}

// ---------------- Pass C: inverse row FFT -> real output ----------------
__global__ __launch_bounds__(256) void fft_rows_inv_kernel(const float2* __restrict__ freq,
                                                           float* __restrict__ out)
{
    __shared__ float2 s[2][NBOX];
    __shared__ float2 tw[128];
    int tid = threadIdx.x;
    int tx = tid & 127, ty = tid >> 7;
    init_tw(tw, tid);
    int row = blockIdx.x * 2 + ty;
    const float2* rp = freq + (size_t)row * NBOX;
    s[ty][tx]       = rp[tx];
    s[ty][tx + 128] = rp[tx + 128];
    __syncthreads();
    fft_dit_t(s[ty], tw, tx);
    const float inv = 1.0f / 256.0f;
    out[(size_t)row * NBOX + tx]       = s[ty][tx].x * inv;
    out[(size_t)row * NBOX + tx + 128] = s[ty][tx + 128].x * inv;
}

extern "C" void kernel_launch(void* const* d_in, const int* in_sizes, int n_in,
                              void* d_out, int out_size, void* d_ws, size_t ws_size,
                              hipStream_t stream)
{
    (void)in_sizes; (void)n_in; (void)out_size;
    const float* z_x     = (const float*)d_in[0];
    const float* z_y     = (const float*)d_in[1];
    const float* z_z     = (const float*)d_in[2];
    const float* Zb      = (const float*)d_in[3];
    const float* coords  = (const float*)d_in[4];
    const float* weights = (const float*)d_in[5];
    const float* R       = (const float*)d_in[6];
    const float* shifts  = (const float*)d_in[7];
    const float* ctf     = (const float*)d_in[8];
    float* out = (float*)d_out;

    const size_t NELEM = (size_t)NIMG * NBOX * NBOX;           // 2,097,152
    const size_t NPAIR = (size_t)NIMG * NPTS;                  // 9.6 M
    char* base = (char*)d_ws;
    float* img  = (float*)base;                                 // 8 MB
    u64*   recs = (u64*)(base + 8388608);                       // 76.8 MB
    float* ubuf = (float*)(base + 8388608 + 76800000);          // 8 KB
    float* vbuf = ubuf + NIMG * NL;                             // 8 KB
    float4* hdrbuf = (float4*)(vbuf + NIMG * NL);               // 1 KB
    // freq aliases recs (recs dead after splat2; freq written after)
    float2* freq = (float2*)(base + 8388608);                   // 16.78 MB < 76.8 MB
    const size_t required = 8388608 + 76800000 + NIMG * NL * 8 + NIMG * 2 * 16;

    zero_kernel<<<(int)(NELEM / 4 + 255) / 256, 256, 0, stream>>>((float4*)img, (int)(NELEM / 4));

    if (ws_size >= required) {
        uvprep_kernel<<<1, 256, 0, stream>>>(z_x, z_y, z_z, R, shifts, ubuf, vbuf, hdrbuf);
        project_kernel<<<(NPTS + 255) / 256, 256, 0, stream>>>(Zb, coords, weights,
                                                               ubuf, vbuf, hdrbuf, recs);
        splat2_kernel<<<NGROUP * BANDS, 256, 0, stream>>>(recs, img);
    } else {
        splat_kernel<<<(NPTS + 255) / 256, 256, 0, stream>>>(z_x, z_y, z_z, Zb, coords,
                                                             weights, R, shifts, img);
    }

    // fused blur + row FFT
    fft_rows_fwd_blur_kernel<<<NIMG * NBOX / 2, 256, 0, stream>>>(img, freq);
    // 8-column fused col-FFT * ctf * inv-col-FFT
    fft_cols_ctf8_kernel<<<NIMG * 32, 1024, 0, stream>>>(freq, ctf);
    // inverse row FFT -> real out
    fft_rows_inv_kernel<<<NIMG * NBOX / 2, 256, 0, stream>>>(freq, out);
}

// Round 15
// 228.955 us; speedup vs baseline: 3.0028x; 1.1358x over previous
//
#include <hip/hip_runtime.h>
#include <hip/hip_bf16.h>

#define NIMG 32
#define NPTS 300000
#define NL   64
#define NBOX 256

#define BANDS  8
#define BROWS  32          // NBOX / BANDS
#define CHUNKS 2
#define CHPTS  (NPTS / CHUNKS)   // 150000
#define NGROUP (NIMG * CHUNKS)   // 64

#define WQS  2047.0f             // 11-bit weight quantization scale (16-bit field headroom)
#define WQI  (1.0f / 2047.0f)

typedef float v2f __attribute__((ext_vector_type(2)));
typedef unsigned long long u64;

__device__ __forceinline__ int rev8(int x) { return (int)(__brev((unsigned)x) >> 24); }

// ---------------- zero fill ----------------
__global__ __launch_bounds__(256) void zero_kernel(float4* p, int n4) {
    int i = blockIdx.x * 256 + threadIdx.x;
    if (i < n4) p[i] = make_float4(0.f, 0.f, 0.f, 0.f);
}

// ---------------- P0: per-image fused coefficients ----------------
__global__ __launch_bounds__(256) void uvprep_kernel(
    const float* __restrict__ z_x, const float* __restrict__ z_y,
    const float* __restrict__ z_z, const float* __restrict__ R,
    const float* __restrict__ shifts,
    float* __restrict__ ubuf, float* __restrict__ vbuf, float4* __restrict__ hdrbuf)
{
    int t = threadIdx.x;
    for (int e = t; e < NIMG * NL; e += 256) {
        int b = e >> 6;
        const float* Rb = R + b * 9;
        float zx = z_x[e], zy = z_y[e], zz = z_z[e];
        ubuf[e] = Rb[0] * zx + Rb[1] * zy + Rb[2] * zz;
        vbuf[e] = Rb[3] * zx + Rb[4] * zy + Rb[5] * zz;
    }
    if (t < NIMG) {
        const float* Rb = R + t * 9;
        hdrbuf[2 * t]     = make_float4(Rb[0], Rb[1], Rb[2], shifts[2 * t]     + 128.f);
        hdrbuf[2 * t + 1] = make_float4(Rb[3], Rb[4], Rb[5], shifts[2 * t + 1] + 128.f);
    }
}

// ---------------- P1: projection -> one u64 record per (image,point) ----------------
// rec = pos(16) | w00q<<16 | w10q<<28 | w01q<<40 | w11q<<52   (11-bit values in 12-bit fields)
__global__ __launch_bounds__(256) void project_kernel(
    const float* __restrict__ Zb, const float* __restrict__ coords,
    const float* __restrict__ weights,
    const float* __restrict__ ubuf, const float* __restrict__ vbuf,
    const float4* __restrict__ hdrbuf,
    u64* __restrict__ recs)
{
    __shared__ float  s_u[NIMG * NL];   // 8 KB
    __shared__ float  s_v[NIMG * NL];   // 8 KB
    __shared__ float4 s_h[NIMG * 2];    // 1 KB

    int tid = threadIdx.x;
    for (int i = tid; i < NIMG * NL; i += 256) {
        s_u[i] = ubuf[i];
        s_v[i] = vbuf[i];
    }
    if (tid < NIMG * 2) s_h[tid] = hdrbuf[tid];
    __syncthreads();

    int p = blockIdx.x * 256 + tid;
    if (p >= NPTS) return;

    v2f zr[32];
    {
        const float4* Zr4 = (const float4*)(Zb + (size_t)p * NL);
        float4 tmp[16];
        #pragma unroll
        for (int i = 0; i < 16; ++i) tmp[i] = Zr4[i];
        const v2f* t2 = (const v2f*)tmp;
        #pragma unroll
        for (int i = 0; i < 32; ++i) zr[i] = t2[i];
    }

    float cx0 = coords[3 * p + 0];
    float cy0 = coords[3 * p + 1];
    float cz0 = coords[3 * p + 2];
    float w   = weights[p];

    for (int b = 0; b < NIMG; ++b) {
        float4 h0 = s_h[2 * b], h1 = s_h[2 * b + 1];
        const v2f* u2 = (const v2f*)(s_u + b * NL);
        const v2f* v2 = (const v2f*)(s_v + b * NL);
        v2f ax = {0.f, 0.f}, ay = {0.f, 0.f};
        #pragma unroll
        for (int i = 0; i < 32; ++i) {
            ax += u2[i] * zr[i];
            ay += v2[i] * zr[i];
        }
        float px = fmaf(h0.x, cx0, fmaf(h0.y, cy0, fmaf(h0.z, cz0, h0.w))) + ax.x + ax.y;
        float py = fmaf(h1.x, cx0, fmaf(h1.y, cy0, fmaf(h1.z, cz0, h1.w))) + ay.x + ay.y;

        float x0f = floorf(px), y0f = floorf(py);
        float fx = px - x0f, fy = py - y0f;
        int xi0 = min(max((int)x0f, 0), NBOX - 1);
        int yi0 = min(max((int)y0f, 0), NBOX - 1);
        float w00 = w * (1.f - fx) * (1.f - fy);
        float w10 = w * fx * (1.f - fy);
        float w01 = w * (1.f - fx) * fy;
        float w11 = w * fx * fy;
        if (xi0 == NBOX - 1) {        // xi1 clamps onto xi0: fold right column left
            w00 += w10; w10 = 0.f;
            w01 += w11; w11 = 0.f;
        }
        if (yi0 == NBOX - 1) {        // yi1 clamps onto yi0: fold bottom row up
            w00 += w01; w01 = 0.f;
            w10 += w11; w11 = 0.f;
        }
        u64 rec = (u64)(unsigned)(xi0 | (yi0 << 8))
                | ((u64)(unsigned)(w00 * WQS + 0.5f) << 16)
                | ((u64)(unsigned)(w10 * WQS + 0.5f) << 28)
                | ((u64)(unsigned)(w01 * WQS + 0.5f) << 40)
                | ((u64)(unsigned)(w11 * WQS + 0.5f) << 52);
        recs[(size_t)b * NPTS + p] = rec;
    }
}

// ---------------- P2: band splat, ONE 2x2-quad u64 atomic per point-image ----------------
// Four quad views (x-parity x y-parity), each u64 = 4 x 16-bit fields
// field = rowfield*2 + colfield; rowfield 0 = upper row (yi0), colfield 0 = left col (xi0).
// VA: rows(2i,2i+1)   cols(2j,2j+1)   — r0 even, xi0 even
// VB: rows(2i,2i+1)   cols(2j-1,2j)   — r0 even, xi0 odd
// VC: rows(2i+1,2i+2) cols(2j,2j+1)   — r0 odd,  xi0 even   (row 32 = band halo)
// VD: rows(2i+1,2i+2) cols(2j-1,2j)   — r0 odd,  xi0 odd
__global__ __launch_bounds__(256) void splat2_kernel(
    const u64* __restrict__ recs, float* __restrict__ img)
{
    __shared__ u64 VA[16 * 128];   // 16 KB
    __shared__ u64 VB[16 * 129];   // 16.1 KB
    __shared__ u64 VC[16 * 128];   // 16 KB
    __shared__ u64 VD[16 * 129];   // 16.1 KB
    int tid = threadIdx.x;
    int id = blockIdx.x;
    int band = id >> 6;           // 0..7
    int g    = id & 63;           // group = b*CHUNKS + c
    int b = g >> 1, c = g & 1;

    for (int i = tid; i < 16 * 128; i += 256) { VA[i] = 0ULL; VC[i] = 0ULL; }
    for (int i = tid; i < 16 * 129; i += 256) { VB[i] = 0ULL; VD[i] = 0ULL; }
    __syncthreads();

    const int y_lo = band * BROWS;
    const u64* rp = recs + (size_t)b * NPTS + (size_t)c * CHPTS;

    for (int i = 4 * tid; i < CHPTS; i += 1024) {
        ulonglong2 R01 = *(const ulonglong2*)(rp + i);       // points i, i+1
        ulonglong2 R23 = *(const ulonglong2*)(rp + i + 2);   // points i+2, i+3
        u64 Ra[4] = {R01.x, R01.y, R23.x, R23.y};
        #pragma unroll
        for (int k = 0; k < 4; ++k) {
            u64 rec = Ra[k];
            unsigned ps = (unsigned)rec & 0xFFFFu;
            int xi0 = ps & 255;
            int yi0 = ps >> 8;
            int r0 = yi0 - y_lo;
            if ((unsigned)r0 >= BROWS) continue;   // single ownership test
            u64 val = ((rec >> 16) & 0xFFFULL)
                    | (((rec >> 28) & 0xFFFULL) << 16)
                    | (((rec >> 40) & 0xFFFULL) << 32)
                    | (((rec >> 52) & 0xFFFULL) << 48);
            int qr = r0 >> 1;                       // uniform for even/odd
            int qc = (xi0 + (xi0 & 1)) >> 1;
            bool xodd = (xi0 & 1), yodd = (r0 & 1);
            u64* base = yodd ? (xodd ? VD : VC) : (xodd ? VB : VA);
            int stride = xodd ? 129 : 128;
            atomicAdd(&base[qr * stride + qc], val);
        }
    }
    __syncthreads();
    // flush 33 rows (incl. halo row 32) with global atomic add
    int nrows = min(33, NBOX - y_lo);
    float* ib = img + (size_t)b * NBOX * NBOX + (size_t)y_lo * NBOX;
    for (int i = tid; i < nrows * NBOX; i += 256) {
        int r = i >> 8, x = i & 255;
        int fc0 = x & 1;          // col field in VA/VC
        int fc1 = fc0 ^ 1;        // col field in VB/VD
        int ja = x >> 1;
        int jb = (x + 1) >> 1;
        unsigned acc = 0;
        if (r < 32) {
            int fr = (r & 1) << 1;
            acc += (unsigned)((VA[(r >> 1) * 128 + ja] >> (16 * (fr | fc0))) & 0xFFFFu);
            acc += (unsigned)((VB[(r >> 1) * 129 + jb] >> (16 * (fr | fc1))) & 0xFFFFu);
        }
        if (r >= 1) {
            int fr = ((r & 1) ^ 1) << 1;
            acc += (unsigned)((VC[((r - 1) >> 1) * 128 + ja] >> (16 * (fr | fc0))) & 0xFFFFu);
            acc += (unsigned)((VD[((r - 1) >> 1) * 129 + jb] >> (16 * (fr | fc1))) & 0xFFFFu);
        }
        if (acc) unsafeAtomicAdd(ib + i, (float)acc * WQI);
    }
}

// ---------------- fallback: fused splat with global atomics (small ws) ----------------
__global__ __launch_bounds__(256) void splat_kernel(
    const float* __restrict__ z_x, const float* __restrict__ z_y,
    const float* __restrict__ z_z, const float* __restrict__ Zb,
    const float* __restrict__ coords, const float* __restrict__ weights,
    const float* __restrict__ R, const float* __restrict__ shifts,
    float* __restrict__ img)
{
    __shared__ float s_z[3][NIMG][NL];
    __shared__ float s_R[NIMG][9];
    __shared__ float s_sh[NIMG][2];

    int tid = threadIdx.x;
    for (int i = tid; i < NIMG * NL; i += 256) {
        (&s_z[0][0][0])[i] = z_x[i];
        (&s_z[1][0][0])[i] = z_y[i];
        (&s_z[2][0][0])[i] = z_z[i];
    }
    for (int i = tid; i < NIMG * 9; i += 256) (&s_R[0][0])[i] = R[i];
    if (tid < NIMG * 2) (&s_sh[0][0])[tid] = shifts[tid];
    __syncthreads();

    int p = blockIdx.x * 256 + tid;
    if (p >= NPTS) return;

    float4 zr[16];
    const float4* Zr4 = (const float4*)(Zb + (size_t)p * NL);
    #pragma unroll
    for (int i = 0; i < 16; ++i) zr[i] = Zr4[i];

    float cx0 = coords[3 * p + 0];
    float cy0 = coords[3 * p + 1];
    float cz0 = coords[3 * p + 2];
    float w   = weights[p];

    for (int b = 0; b < NIMG; ++b) {
        const float4* zx4 = (const float4*)s_z[0][b];
        const float4* zy4 = (const float4*)s_z[1][b];
        const float4* zz4 = (const float4*)s_z[2][b];
        float dx = 0.f, dy = 0.f, dz = 0.f;
        #pragma unroll
        for (int i = 0; i < 16; ++i) {
            float4 a = zx4[i];
            dx += a.x * zr[i].x + a.y * zr[i].y + a.z * zr[i].z + a.w * zr[i].w;
            float4 bb = zy4[i];
            dy += bb.x * zr[i].x + bb.y * zr[i].y + bb.z * zr[i].z + bb.w * zr[i].w;
            float4 c = zz4[i];
            dz += c.x * zr[i].x + c.y * zr[i].y + c.z * zr[i].z + c.w * zr[i].w;
        }
        float cx = cx0 + dx, cy = cy0 + dy, cz = cz0 + dz;
        const float* Rb = s_R[b];
        float px = Rb[0] * cx + Rb[1] * cy + Rb[2] * cz + s_sh[b][0] + 128.0f;
        float py = Rb[3] * cx + Rb[4] * cy + Rb[5] * cz + s_sh[b][1] + 128.0f;

        float x0 = floorf(px), y0 = floorf(py);
        float fx = px - x0, fy = py - y0;
        int xi0 = min(max((int)x0, 0), NBOX - 1);
        int yi0 = min(max((int)y0, 0), NBOX - 1);
        int xi1 = min(xi0 + 1, NBOX - 1);
        int yi1 = min(yi0 + 1, NBOX - 1);

        float* ib = img + (size_t)b * NBOX * NBOX;
        unsafeAtomicAdd(ib + yi0 * NBOX + xi0, w * (1.f - fx) * (1.f - fy));
        unsafeAtomicAdd(ib + yi0 * NBOX + xi1, w * fx * (1.f - fy));
        unsafeAtomicAdd(ib + yi1 * NBOX + xi0, w * (1.f - fx) * fy);
        unsafeAtomicAdd(ib + yi1 * NBOX + xi1, w * fx * fy);
    }
}

// ---------------- 256-pt FFT helpers (AOS float2, LDS twiddle) ----------------
__device__ __forceinline__ void fft_dif_t(float2* s, const float2* tw, int t) {
    #pragma unroll
    for (int st = 7; st >= 0; --st) {
        int half = 1 << st;
        int j  = t & (half - 1);
        int i1 = ((t >> st) << (st + 1)) + j;
        int i2 = i1 + half;
        float2 a = s[i1], b = s[i2];
        float2 w = tw[j << (7 - st)];
        float dxr = a.x - b.x, dxi = a.y - b.y;
        s[i1] = make_float2(a.x + b.x, a.y + b.y);
        s[i2] = make_float2(w.x * dxr - w.y * dxi, w.x * dxi + w.y * dxr);
        __syncthreads();
    }
}

__device__ __forceinline__ void fft_dit_t(float2* s, const float2* tw, int t) {
    #pragma unroll
    for (int st = 0; st < 8; ++st) {
        int half = 1 << st;
        int j  = t & (half - 1);
        int i1 = ((t >> st) << (st + 1)) + j;
        int i2 = i1 + half;
        float2 a = s[i1], b = s[i2];
        float2 w = tw[j << (7 - st)];
        float cs = w.x, sn = -w.y;
        float tr = cs * b.x - sn * b.y;
        float ti = cs * b.y + sn * b.x;
        s[i1] = make_float2(a.x + tr, a.y + ti);
        s[i2] = make_float2(a.x - tr, a.y - ti);
        __syncthreads();
    }
}

// ---------------- SOA FFT helpers (8-col kernel) ----------------
__device__ __forceinline__ void fft_dif_soa(float* re, float* im, const float2* tw, int t) {
    #pragma unroll
    for (int st = 7; st >= 0; --st) {
        int half = 1 << st;
        int j  = t & (half - 1);
        int i1 = ((t >> st) << (st + 1)) + j;
        int i2 = i1 + half;
        float ar = re[i1], ai = im[i1], br = re[i2], bi = im[i2];
        float2 w = tw[j << (7 - st)];
        float dr = ar - br, di = ai - bi;
        re[i1] = ar + br;  im[i1] = ai + bi;
        re[i2] = w.x * dr - w.y * di;
        im[i2] = w.x * di + w.y * dr;
        __syncthreads();
    }
}

__device__ __forceinline__ void fft_dit_soa(float* re, float* im, const float2* tw, int t) {
    #pragma unroll
    for (int st = 0; st < 8; ++st) {
        int half = 1 << st;
        int j  = t & (half - 1);
        int i1 = ((t >> st) << (st + 1)) + j;
        int i2 = i1 + half;
        float ar = re[i1], ai = im[i1], br = re[i2], bi = im[i2];
        float2 w = tw[j << (7 - st)];
        float cs = w.x, sn = -w.y;
        float tr = cs * br - sn * bi;
        float ti = cs * bi + sn * br;
        re[i1] = ar + tr;  im[i1] = ai + ti;
        re[i2] = ar - tr;  im[i2] = ai - ti;
        __syncthreads();
    }
}

__device__ __forceinline__ void init_tw(float2* tw, int tid) {
    if (tid < 128) {
        float sn, cs;
        sincosf(-6.283185307179586f * (float)tid * (1.0f / 256.0f), &sn, &cs);
        tw[tid] = make_float2(cs, sn);
    }
}

// ---------------- Pass A: fused 5x5 blur + forward row FFT ----------------
__global__ __launch_bounds__(256) void fft_rows_fwd_blur_kernel(const float* __restrict__ img,
                                                                float2* __restrict__ freq)
{
    __shared__ float2 s[2][NBOX];
    __shared__ float  sb[2][NBOX];
    __shared__ float2 tw[128];
    int tid = threadIdx.x;
    int tx = tid & 127, ty = tid >> 7;
    init_tw(tw, tid);
    int row = blockIdx.x * 2 + ty;     // 0 .. B*N-1
    int b = row >> 8, y = row & (NBOX - 1);
    const float* ib = img + ((size_t)b << 16);
    const float gw[5] = {0.0544886845f, 0.2442013420f, 0.4026199469f,
                         0.2442013420f, 0.0544886845f};
    float acc0 = 0.f, acc1 = 0.f;
    #pragma unroll
    for (int dy = -2; dy <= 2; ++dy) {
        int yy = y + dy;
        if ((unsigned)yy < (unsigned)NBOX) {
            const float* rp = ib + yy * NBOX;
            acc0 += gw[dy + 2] * rp[tx];
            acc1 += gw[dy + 2] * rp[tx + 128];
        }
    }
    sb[ty][tx] = acc0;  sb[ty][tx + 128] = acc1;
    __syncthreads();
    float r0 = 0.f, r1 = 0.f;
    #pragma unroll
    for (int dx = -2; dx <= 2; ++dx) {
        int x0 = tx + dx, x1 = tx + 128 + dx;
        if ((unsigned)x0 < (unsigned)NBOX) r0 += gw[dx + 2] * sb[ty][x0];
        if ((unsigned)x1 < (unsigned)NBOX) r1 += gw[dx + 2] * sb[ty][x1];
    }
    s[ty][tx]       = make_float2(r0, 0.f);
    s[ty][tx + 128] = make_float2(r1, 0.f);
    __syncthreads();
    fft_dif_t(s[ty], tw, tx);
    float2* op = freq + (size_t)row * NBOX;
    op[tx]       = s[ty][tx];
    op[tx + 128] = s[ty][tx + 128];
}

// ---------------- Pass B: 8-column fused fwd-FFT * ctf * inv-FFT ----------------
__global__ __launch_bounds__(1024) void fft_cols_ctf8_kernel(float2* __restrict__ freq,
                                                             const float* __restrict__ ctf)
{
    __shared__ float  s_re[8][257];
    __shared__ float  s_im[8][257];
    __shared__ float2 tw[128];
    int tid = threadIdx.x;
    init_tw(tw, tid);
    int col = tid & 7, j = tid >> 3;          // j in 0..127
    int blk = blockIdx.x;
    int b = blk >> 5;
    int x = ((blk & 31) << 3) + col;          // storage x
    float2* base = freq + ((size_t)b << 16) + x;

    float2 v0 = base[(size_t)j * NBOX];
    float2 v1 = base[(size_t)(j + 128) * NBOX];
    s_re[col][j] = v0.x;        s_im[col][j] = v0.y;
    s_re[col][j + 128] = v1.x;  s_im[col][j + 128] = v1.y;
    __syncthreads();

    fft_dif_soa(s_re[col], s_im[col], tw, j);

    const float* cb = ctf + ((size_t)b << 16) + rev8(x);
    float c0 = cb[rev8(j) * NBOX];
    float c1 = cb[rev8(j + 128) * NBOX];
    s_re[col][j] *= c0;        s_im[col][j] *= c0;
    s_re[col][j + 128] *= c1;  s_im[col][j + 128] *= c1;
    __syncthreads();

    fft_dit_soa(s_re[col], s_im[col], tw, j);

    const float inv = 1.0f / 256.0f;
    base[(size_t)j * NBOX]         = make_float2(s_re[col][j] * inv, s_im[col][j] * inv);
    base[(size_t)(j + 128) * NBOX] = make_float2(s_re[col][j + 128] * inv, s_im[col][j + 128] * inv);
}

// ---------------- Pass C: inverse row FFT -> real output ----------------
__global__ __launch_bounds__(256) void fft_rows_inv_kernel(const float2* __restrict__ freq,
                                                           float* __restrict__ out)
{
    __shared__ float2 s[2][NBOX];
    __shared__ float2 tw[128];
    int tid = threadIdx.x;
    int tx = tid & 127, ty = tid >> 7;
    init_tw(tw, tid);
    int row = blockIdx.x * 2 + ty;
    const float2* rp = freq + (size_t)row * NBOX;
    s[ty][tx]       = rp[tx];
    s[ty][tx + 128] = rp[tx + 128];
    __syncthreads();
    fft_dit_t(s[ty], tw, tx);
    const float inv = 1.0f / 256.0f;
    out[(size_t)row * NBOX + tx]       = s[ty][tx].x * inv;
    out[(size_t)row * NBOX + tx + 128] = s[ty][tx + 128].x * inv;
}

extern "C" void kernel_launch(void* const* d_in, const int* in_sizes, int n_in,
                              void* d_out, int out_size, void* d_ws, size_t ws_size,
                              hipStream_t stream)
{
    (void)in_sizes; (void)n_in; (void)out_size;
    const float* z_x     = (const float*)d_in[0];
    const float* z_y     = (const float*)d_in[1];
    const float* z_z     = (const float*)d_in[2];
    const float* Zb      = (const float*)d_in[3];
    const float* coords  = (const float*)d_in[4];
    const float* weights = (const float*)d_in[5];
    const float* R       = (const float*)d_in[6];
    const float* shifts  = (const float*)d_in[7];
    const float* ctf     = (const float*)d_in[8];
    float* out = (float*)d_out;

    const size_t NELEM = (size_t)NIMG * NBOX * NBOX;           // 2,097,152
    const size_t NPAIR = (size_t)NIMG * NPTS;                  // 9.6 M
    char* base = (char*)d_ws;
    float* img  = (float*)base;                                 // 8 MB
    u64*   recs = (u64*)(base + 8388608);                       // 76.8 MB
    float* ubuf = (float*)(base + 8388608 + 76800000);          // 8 KB
    float* vbuf = ubuf + NIMG * NL;                             // 8 KB
    float4* hdrbuf = (float4*)(vbuf + NIMG * NL);               // 1 KB
    // freq aliases recs (recs dead after splat2; freq written after)
    float2* freq = (float2*)(base + 8388608);                   // 16.78 MB < 76.8 MB
    const size_t required = 8388608 + 76800000 + NIMG * NL * 8 + NIMG * 2 * 16;

    zero_kernel<<<(int)(NELEM / 4 + 255) / 256, 256, 0, stream>>>((float4*)img, (int)(NELEM / 4));

    if (ws_size >= required) {
        uvprep_kernel<<<1, 256, 0, stream>>>(z_x, z_y, z_z, R, shifts, ubuf, vbuf, hdrbuf);
        project_kernel<<<(NPTS + 255) / 256, 256, 0, stream>>>(Zb, coords, weights,
                                                               ubuf, vbuf, hdrbuf, recs);
        splat2_kernel<<<NGROUP * BANDS, 256, 0, stream>>>(recs, img);
    } else {
        splat_kernel<<<(NPTS + 255) / 256, 256, 0, stream>>>(z_x, z_y, z_z, Zb, coords,
                                                             weights, R, shifts, img);
    }

    // fused blur + row FFT
    fft_rows_fwd_blur_kernel<<<NIMG * NBOX / 2, 256, 0, stream>>>(img, freq);
    // 8-column fused col-FFT * ctf * inv-col-FFT
    fft_cols_ctf8_kernel<<<NIMG * 32, 1024, 0, stream>>>(freq, ctf);
    // inverse row FFT -> real out
    fft_rows_inv_kernel<<<NIMG * NBOX / 2, 256, 0, stream>>>(freq, out);
}

// Round 16
// 181.009 us; speedup vs baseline: 3.7982x; 1.2649x over previous
//
#include <hip/hip_runtime.h>
#include <hip/hip_bf16.h>

#define NIMG 32
#define NPTS 300000
#define NL   64
#define NBOX 256

#define BANDS  4
#define BROWS  64          // NBOX / BANDS
#define CHUNKS 2
#define CHPTS  (NPTS / CHUNKS)   // 150000

#define WQS  2047.0f             // 11-bit weight quantization scale (16-bit field headroom)
#define WQI  (1.0f / 2047.0f)

typedef float v2f __attribute__((ext_vector_type(2)));
typedef unsigned long long u64;

__device__ __forceinline__ int rev8(int x) { return (int)(__brev((unsigned)x) >> 24); }

// ---------------- zero fill ----------------
__global__ __launch_bounds__(256) void zero_kernel(float4* p, int n4) {
    int i = blockIdx.x * 256 + threadIdx.x;
    if (i < n4) p[i] = make_float4(0.f, 0.f, 0.f, 0.f);
}

// ---------------- P0: per-image fused coefficients ----------------
__global__ __launch_bounds__(256) void uvprep_kernel(
    const float* __restrict__ z_x, const float* __restrict__ z_y,
    const float* __restrict__ z_z, const float* __restrict__ R,
    const float* __restrict__ shifts,
    float* __restrict__ ubuf, float* __restrict__ vbuf, float4* __restrict__ hdrbuf)
{
    int t = threadIdx.x;
    for (int e = t; e < NIMG * NL; e += 256) {
        int b = e >> 6;
        const float* Rb = R + b * 9;
        float zx = z_x[e], zy = z_y[e], zz = z_z[e];
        ubuf[e] = Rb[0] * zx + Rb[1] * zy + Rb[2] * zz;
        vbuf[e] = Rb[3] * zx + Rb[4] * zy + Rb[5] * zz;
    }
    if (t < NIMG) {
        const float* Rb = R + t * 9;
        hdrbuf[2 * t]     = make_float4(Rb[0], Rb[1], Rb[2], shifts[2 * t]     + 128.f);
        hdrbuf[2 * t + 1] = make_float4(Rb[3], Rb[4], Rb[5], shifts[2 * t + 1] + 128.f);
    }
}

// ---------------- P1: projection -> one u64 record per (image,point) ----------------
// rec = pos(16) | w00q<<16 | w10q<<28 | w01q<<40 | w11q<<52   (11-bit values in 12-bit fields)
__global__ __launch_bounds__(256) void project_kernel(
    const float* __restrict__ Zb, const float* __restrict__ coords,
    const float* __restrict__ weights,
    const float* __restrict__ ubuf, const float* __restrict__ vbuf,
    const float4* __restrict__ hdrbuf,
    u64* __restrict__ recs)
{
    __shared__ float  s_u[NIMG * NL];   // 8 KB
    __shared__ float  s_v[NIMG * NL];   // 8 KB
    __shared__ float4 s_h[NIMG * 2];    // 1 KB

    int tid = threadIdx.x;
    for (int i = tid; i < NIMG * NL; i += 256) {
        s_u[i] = ubuf[i];
        s_v[i] = vbuf[i];
    }
    if (tid < NIMG * 2) s_h[tid] = hdrbuf[tid];
    __syncthreads();

    int p = blockIdx.x * 256 + tid;
    if (p >= NPTS) return;

    v2f zr[32];
    {
        const float4* Zr4 = (const float4*)(Zb + (size_t)p * NL);
        float4 tmp[16];
        #pragma unroll
        for (int i = 0; i < 16; ++i) tmp[i] = Zr4[i];
        const v2f* t2 = (const v2f*)tmp;
        #pragma unroll
        for (int i = 0; i < 32; ++i) zr[i] = t2[i];
    }

    float cx0 = coords[3 * p + 0];
    float cy0 = coords[3 * p + 1];
    float cz0 = coords[3 * p + 2];
    float w   = weights[p];

    for (int b = 0; b < NIMG; ++b) {
        float4 h0 = s_h[2 * b], h1 = s_h[2 * b + 1];
        const v2f* u2 = (const v2f*)(s_u + b * NL);
        const v2f* v2 = (const v2f*)(s_v + b * NL);
        v2f ax = {0.f, 0.f}, ay = {0.f, 0.f};
        #pragma unroll
        for (int i = 0; i < 32; ++i) {
            ax += u2[i] * zr[i];
            ay += v2[i] * zr[i];
        }
        float px = fmaf(h0.x, cx0, fmaf(h0.y, cy0, fmaf(h0.z, cz0, h0.w))) + ax.x + ax.y;
        float py = fmaf(h1.x, cx0, fmaf(h1.y, cy0, fmaf(h1.z, cz0, h1.w))) + ay.x + ay.y;

        float x0f = floorf(px), y0f = floorf(py);
        float fx = px - x0f, fy = py - y0f;
        int xi0 = min(max((int)x0f, 0), NBOX - 1);
        int yi0 = min(max((int)y0f, 0), NBOX - 1);
        float w00 = w * (1.f - fx) * (1.f - fy);
        float w10 = w * fx * (1.f - fy);
        float w01 = w * (1.f - fx) * fy;
        float w11 = w * fx * fy;
        if (xi0 == NBOX - 1) {        // xi1 clamps onto xi0: fold right column left
            w00 += w10; w10 = 0.f;
            w01 += w11; w11 = 0.f;
        }
        if (yi0 == NBOX - 1) {        // yi1 clamps onto yi0: fold bottom row up
            w00 += w01; w01 = 0.f;
            w10 += w11; w11 = 0.f;
        }
        u64 rec = (u64)(unsigned)(xi0 | (yi0 << 8))
                | ((u64)(unsigned)(w00 * WQS + 0.5f) << 16)
                | ((u64)(unsigned)(w10 * WQS + 0.5f) << 28)
                | ((u64)(unsigned)(w01 * WQS + 0.5f) << 40)
                | ((u64)(unsigned)(w11 * WQS + 0.5f) << 52);
        recs[(size_t)b * NPTS + p] = rec;
    }
}

// ---------------- P2: band splat, ONE 2x2-quad u64 atomic per point-image ----------------
// BANDS=4, BROWS=64, quad views total 128.5 KB LDS, 1024-thread blocks (1 block/CU).
// VA: rows(2i,2i+1)   cols(2j,2j+1)   — r0 even, xi0 even
// VB: rows(2i,2i+1)   cols(2j-1,2j)   — r0 even, xi0 odd
// VC: rows(2i+1,2i+2) cols(2j,2j+1)   — r0 odd,  xi0 even   (row 64 = band halo)
// VD: rows(2i+1,2i+2) cols(2j-1,2j)   — r0 odd,  xi0 odd
__global__ __launch_bounds__(1024) void splat2_kernel(
    const u64* __restrict__ recs, float* __restrict__ img)
{
    __shared__ u64 VA[32 * 128];   // 32 KB
    __shared__ u64 VB[32 * 129];   // 32.25 KB
    __shared__ u64 VC[32 * 128];   // 32 KB
    __shared__ u64 VD[32 * 129];   // 32.25 KB
    int tid = threadIdx.x;
    int id = blockIdx.x;           // band*64 + b*CHUNKS + c  (256 blocks)
    int band = id >> 6;            // 0..3
    int g    = id & 63;
    int b = g >> 1, c = g & 1;

    for (int i = tid; i < 32 * 128; i += 1024) { VA[i] = 0ULL; VC[i] = 0ULL; }
    for (int i = tid; i < 32 * 129; i += 1024) { VB[i] = 0ULL; VD[i] = 0ULL; }
    __syncthreads();

    const int y_lo = band * BROWS;
    const u64* rp = recs + (size_t)b * NPTS + (size_t)c * CHPTS;

    for (int i = 4 * tid; i < CHPTS; i += 4096) {
        ulonglong2 R01 = *(const ulonglong2*)(rp + i);       // points i, i+1
        ulonglong2 R23 = *(const ulonglong2*)(rp + i + 2);   // points i+2, i+3
        u64 Ra[4] = {R01.x, R01.y, R23.x, R23.y};
        #pragma unroll
        for (int k = 0; k < 4; ++k) {
            u64 rec = Ra[k];
            unsigned ps = (unsigned)rec & 0xFFFFu;
            int xi0 = ps & 255;
            int yi0 = ps >> 8;
            int r0 = yi0 - y_lo;
            if ((unsigned)r0 >= BROWS) continue;   // single ownership test
            u64 val = ((rec >> 16) & 0xFFFULL)
                    | (((rec >> 28) & 0xFFFULL) << 16)
                    | (((rec >> 40) & 0xFFFULL) << 32)
                    | (((rec >> 52) & 0xFFFULL) << 48);
            int qr = r0 >> 1;
            int qc = (xi0 + (xi0 & 1)) >> 1;
            bool xodd = (xi0 & 1), yodd = (r0 & 1);
            u64* base = yodd ? (xodd ? VD : VC) : (xodd ? VB : VA);
            int stride = xodd ? 129 : 128;
            atomicAdd(&base[qr * stride + qc], val);
        }
    }
    __syncthreads();
    // flush 65 rows (incl. halo row 64) with global atomic add
    int nrows = min(BROWS + 1, NBOX - y_lo);
    float* ib = img + (size_t)b * NBOX * NBOX + (size_t)y_lo * NBOX;
    for (int i = tid; i < nrows * NBOX; i += 1024) {
        int r = i >> 8, x = i & 255;
        int fc0 = x & 1;          // col field in VA/VC
        int fc1 = fc0 ^ 1;        // col field in VB/VD
        int ja = x >> 1;
        int jb = (x + 1) >> 1;
        unsigned acc = 0;
        if (r < BROWS) {
            int fr = (r & 1) << 1;
            acc += (unsigned)((VA[(r >> 1) * 128 + ja] >> (16 * (fr | fc0))) & 0xFFFFu);
            acc += (unsigned)((VB[(r >> 1) * 129 + jb] >> (16 * (fr | fc1))) & 0xFFFFu);
        }
        if (r >= 1) {
            int fr = ((r & 1) ^ 1) << 1;
            acc += (unsigned)((VC[((r - 1) >> 1) * 128 + ja] >> (16 * (fr | fc0))) & 0xFFFFu);
            acc += (unsigned)((VD[((r - 1) >> 1) * 129 + jb] >> (16 * (fr | fc1))) & 0xFFFFu);
        }
        if (acc) unsafeAtomicAdd(ib + i, (float)acc * WQI);
    }
}

// ---------------- fallback: fused splat with global atomics (small ws) ----------------
__global__ __launch_bounds__(256) void splat_kernel(
    const float* __restrict__ z_x, const float* __restrict__ z_y,
    const float* __restrict__ z_z, const float* __restrict__ Zb,
    const float* __restrict__ coords, const float* __restrict__ weights,
    const float* __restrict__ R, const float* __restrict__ shifts,
    float* __restrict__ img)
{
    __shared__ float s_z[3][NIMG][NL];
    __shared__ float s_R[NIMG][9];
    __shared__ float s_sh[NIMG][2];

    int tid = threadIdx.x;
    for (int i = tid; i < NIMG * NL; i += 256) {
        (&s_z[0][0][0])[i] = z_x[i];
        (&s_z[1][0][0])[i] = z_y[i];
        (&s_z[2][0][0])[i] = z_z[i];
    }
    for (int i = tid; i < NIMG * 9; i += 256) (&s_R[0][0])[i] = R[i];
    if (tid < NIMG * 2) (&s_sh[0][0])[tid] = shifts[tid];
    __syncthreads();

    int p = blockIdx.x * 256 + tid;
    if (p >= NPTS) return;

    float4 zr[16];
    const float4* Zr4 = (const float4*)(Zb + (size_t)p * NL);
    #pragma unroll
    for (int i = 0; i < 16; ++i) zr[i] = Zr4[i];

    float cx0 = coords[3 * p + 0];
    float cy0 = coords[3 * p + 1];
    float cz0 = coords[3 * p + 2];
    float w   = weights[p];

    for (int b = 0; b < NIMG; ++b) {
        const float4* zx4 = (const float4*)s_z[0][b];
        const float4* zy4 = (const float4*)s_z[1][b];
        const float4* zz4 = (const float4*)s_z[2][b];
        float dx = 0.f, dy = 0.f, dz = 0.f;
        #pragma unroll
        for (int i = 0; i < 16; ++i) {
            float4 a = zx4[i];
            dx += a.x * zr[i].x + a.y * zr[i].y + a.z * zr[i].z + a.w * zr[i].w;
            float4 bb = zy4[i];
            dy += bb.x * zr[i].x + bb.y * zr[i].y + bb.z * zr[i].z + bb.w * zr[i].w;
            float4 c = zz4[i];
            dz += c.x * zr[i].x + c.y * zr[i].y + c.z * zr[i].z + c.w * zr[i].w;
        }
        float cx = cx0 + dx, cy = cy0 + dy, cz = cz0 + dz;
        const float* Rb = s_R[b];
        float px = Rb[0] * cx + Rb[1] * cy + Rb[2] * cz + s_sh[b][0] + 128.0f;
        float py = Rb[3] * cx + Rb[4] * cy + Rb[5] * cz + s_sh[b][1] + 128.0f;

        float x0 = floorf(px), y0 = floorf(py);
        float fx = px - x0, fy = py - y0;
        int xi0 = min(max((int)x0, 0), NBOX - 1);
        int yi0 = min(max((int)y0, 0), NBOX - 1);
        int xi1 = min(xi0 + 1, NBOX - 1);
        int yi1 = min(yi0 + 1, NBOX - 1);

        float* ib = img + (size_t)b * NBOX * NBOX;
        unsafeAtomicAdd(ib + yi0 * NBOX + xi0, w * (1.f - fx) * (1.f - fy));
        unsafeAtomicAdd(ib + yi0 * NBOX + xi1, w * fx * (1.f - fy));
        unsafeAtomicAdd(ib + yi1 * NBOX + xi0, w * (1.f - fx) * fy);
        unsafeAtomicAdd(ib + yi1 * NBOX + xi1, w * fx * fy);
    }
}

// ---------------- 256-pt FFT helpers (AOS float2, LDS twiddle) ----------------
__device__ __forceinline__ void fft_dif_t(float2* s, const float2* tw, int t) {
    #pragma unroll
    for (int st = 7; st >= 0; --st) {
        int half = 1 << st;
        int j  = t & (half - 1);
        int i1 = ((t >> st) << (st + 1)) + j;
        int i2 = i1 + half;
        float2 a = s[i1], b = s[i2];
        float2 w = tw[j << (7 - st)];
        float dxr = a.x - b.x, dxi = a.y - b.y;
        s[i1] = make_float2(a.x + b.x, a.y + b.y);
        s[i2] = make_float2(w.x * dxr - w.y * dxi, w.x * dxi + w.y * dxr);
        __syncthreads();
    }
}

__device__ __forceinline__ void fft_dit_t(float2* s, const float2* tw, int t) {
    #pragma unroll
    for (int st = 0; st < 8; ++st) {
        int half = 1 << st;
        int j  = t & (half - 1);
        int i1 = ((t >> st) << (st + 1)) + j;
        int i2 = i1 + half;
        float2 a = s[i1], b = s[i2];
        float2 w = tw[j << (7 - st)];
        float cs = w.x, sn = -w.y;
        float tr = cs * b.x - sn * b.y;
        float ti = cs * b.y + sn * b.x;
        s[i1] = make_float2(a.x + tr, a.y + ti);
        s[i2] = make_float2(a.x - tr, a.y - ti);
        __syncthreads();
    }
}

// ---------------- SOA FFT helpers (8-col kernel) ----------------
__device__ __forceinline__ void fft_dif_soa(float* re, float* im, const float2* tw, int t) {
    #pragma unroll
    for (int st = 7; st >= 0; --st) {
        int half = 1 << st;
        int j  = t & (half - 1);
        int i1 = ((t >> st) << (st + 1)) + j;
        int i2 = i1 + half;
        float ar = re[i1], ai = im[i1], br = re[i2], bi = im[i2];
        float2 w = tw[j << (7 - st)];
        float dr = ar - br, di = ai - bi;
        re[i1] = ar + br;  im[i1] = ai + bi;
        re[i2] = w.x * dr - w.y * di;
        im[i2] = w.x * di + w.y * dr;
        __syncthreads();
    }
}

__device__ __forceinline__ void fft_dit_soa(float* re, float* im, const float2* tw, int t) {
    #pragma unroll
    for (int st = 0; st < 8; ++st) {
        int half = 1 << st;
        int j  = t & (half - 1);
        int i1 = ((t >> st) << (st + 1)) + j;
        int i2 = i1 + half;
        float ar = re[i1], ai = im[i1], br = re[i2], bi = im[i2];
        float2 w = tw[j << (7 - st)];
        float cs = w.x, sn = -w.y;
        float tr = cs * br - sn * bi;
        float ti = cs * bi + sn * br;
        re[i1] = ar + tr;  im[i1] = ai + ti;
        re[i2] = ar - tr;  im[i2] = ai - ti;
        __syncthreads();
    }
}

__device__ __forceinline__ void init_tw(float2* tw, int tid) {
    if (tid < 128) {
        float sn, cs;
        sincosf(-6.283185307179586f * (float)tid * (1.0f / 256.0f), &sn, &cs);
        tw[tid] = make_float2(cs, sn);
    }
}

// ---------------- Pass A: fused 5x5 blur + forward row FFT ----------------
__global__ __launch_bounds__(256) void fft_rows_fwd_blur_kernel(const float* __restrict__ img,
                                                                float2* __restrict__ freq)
{
    __shared__ float2 s[2][NBOX];
    __shared__ float  sb[2][NBOX];
    __shared__ float2 tw[128];
    int tid = threadIdx.x;
    int tx = tid & 127, ty = tid >> 7;
    init_tw(tw, tid);
    int row = blockIdx.x * 2 + ty;     // 0 .. B*N-1
    int b = row >> 8, y = row & (NBOX - 1);
    const float* ib = img + ((size_t)b << 16);
    const float gw[5] = {0.0544886845f, 0.2442013420f, 0.4026199469f,
                         0.2442013420f, 0.0544886845f};
    float acc0 = 0.f, acc1 = 0.f;
    #pragma unroll
    for (int dy = -2; dy <= 2; ++dy) {
        int yy = y + dy;
        if ((unsigned)yy < (unsigned)NBOX) {
            const float* rp = ib + yy * NBOX;
            acc0 += gw[dy + 2] * rp[tx];
            acc1 += gw[dy + 2] * rp[tx + 128];
        }
    }
    sb[ty][tx] = acc0;  sb[ty][tx + 128] = acc1;
    __syncthreads();
    float r0 = 0.f, r1 = 0.f;
    #pragma unroll
    for (int dx = -2; dx <= 2; ++dx) {
        int x0 = tx + dx, x1 = tx + 128 + dx;
        if ((unsigned)x0 < (unsigned)NBOX) r0 += gw[dx + 2] * sb[ty][x0];
        if ((unsigned)x1 < (unsigned)NBOX) r1 += gw[dx + 2] * sb[ty][x1];
    }
    s[ty][tx]       = make_float2(r0, 0.f);
    s[ty][tx + 128] = make_float2(r1, 0.f);
    __syncthreads();
    fft_dif_t(s[ty], tw, tx);
    float2* op = freq + (size_t)row * NBOX;
    op[tx]       = s[ty][tx];
    op[tx + 128] = s[ty][tx + 128];
}

// ---------------- Pass B: 8-column fused fwd-FFT * ctf * inv-FFT ----------------
__global__ __launch_bounds__(1024) void fft_cols_ctf8_kernel(float2* __restrict__ freq,
                                                             const float* __restrict__ ctf)
{
    __shared__ float  s_re[8][257];
    __shared__ float  s_im[8][257];
    __shared__ float2 tw[128];
    int tid = threadIdx.x;
    init_tw(tw, tid);
    int col = tid & 7, j = tid >> 3;          // j in 0..127
    int blk = blockIdx.x;
    int b = blk >> 5;
    int x = ((blk & 31) << 3) + col;          // storage x
    float2* base = freq + ((size_t)b << 16) + x;

    float2 v0 = base[(size_t)j * NBOX];
    float2 v1 = base[(size_t)(j + 128) * NBOX];
    s_re[col][j] = v0.x;        s_im[col][j] = v0.y;
    s_re[col][j + 128] = v1.x;  s_im[col][j + 128] = v1.y;
    __syncthreads();

    fft_dif_soa(s_re[col], s_im[col], tw, j);

    const float* cb = ctf + ((size_t)b << 16) + rev8(x);
    float c0 = cb[rev8(j) * NBOX];
    float c1 = cb[rev8(j + 128) * NBOX];
    s_re[col][j] *= c0;        s_im[col][j] *= c0;
    s_re[col][j + 128] *= c1;  s_im[col][j + 128] *= c1;
    __syncthreads();

    fft_dit_soa(s_re[col], s_im[col], tw, j);

    const float inv = 1.0f / 256.0f;
    base[(size_t)j * NBOX]         = make_float2(s_re[col][j] * inv, s_im[col][j] * inv);
    base[(size_t)(j + 128) * NBOX] = make_float2(s_re[col][j + 128] * inv, s_im[col][j + 128] * inv);
}

// ---------------- Pass C: inverse row FFT -> real output ----------------
__global__ __launch_bounds__(256) void fft_rows_inv_kernel(const float2* __restrict__ freq,
                                                           float* __restrict__ out)
{
    __shared__ float2 s[2][NBOX];
    __shared__ float2 tw[128];
    int tid = threadIdx.x;
    int tx = tid & 127, ty = tid >> 7;
    init_tw(tw, tid);
    int row = blockIdx.x * 2 + ty;
    const float2* rp = freq + (size_t)row * NBOX;
    s[ty][tx]       = rp[tx];
    s[ty][tx + 128] = rp[tx + 128];
    __syncthreads();
    fft_dit_t(s[ty], tw, tx);
    const float inv = 1.0f / 256.0f;
    out[(size_t)row * NBOX + tx]       = s[ty][tx].x * inv;
    out[(size_t)row * NBOX + tx + 128] = s[ty][tx + 128].x * inv;
}

extern "C" void kernel_launch(void* const* d_in, const int* in_sizes, int n_in,
                              void* d_out, int out_size, void* d_ws, size_t ws_size,
                              hipStream_t stream)
{
    (void)in_sizes; (void)n_in; (void)out_size;
    const float* z_x     = (const float*)d_in[0];
    const float* z_y     = (const float*)d_in[1];
    const float* z_z     = (const float*)d_in[2];
    const float* Zb      = (const float*)d_in[3];
    const float* coords  = (const float*)d_in[4];
    const float* weights = (const float*)d_in[5];
    const float* R       = (const float*)d_in[6];
    const float* shifts  = (const float*)d_in[7];
    const float* ctf     = (const float*)d_in[8];
    float* out = (float*)d_out;

    const size_t NELEM = (size_t)NIMG * NBOX * NBOX;           // 2,097,152
    const size_t NPAIR = (size_t)NIMG * NPTS;                  // 9.6 M
    char* base = (char*)d_ws;
    float* img  = (float*)base;                                 // 8 MB
    u64*   recs = (u64*)(base + 8388608);                       // 76.8 MB
    float* ubuf = (float*)(base + 8388608 + 76800000);          // 8 KB
    float* vbuf = ubuf + NIMG * NL;                             // 8 KB
    float4* hdrbuf = (float4*)(vbuf + NIMG * NL);               // 1 KB
    // freq aliases recs (recs dead after splat2; freq written after)
    float2* freq = (float2*)(base + 8388608);                   // 16.78 MB < 76.8 MB
    const size_t required = 8388608 + 76800000 + NIMG * NL * 8 + NIMG * 2 * 16;

    zero_kernel<<<(int)(NELEM / 4 + 255) / 256, 256, 0, stream>>>((float4*)img, (int)(NELEM / 4));

    if (ws_size >= required) {
        uvprep_kernel<<<1, 256, 0, stream>>>(z_x, z_y, z_z, R, shifts, ubuf, vbuf, hdrbuf);
        project_kernel<<<(NPTS + 255) / 256, 256, 0, stream>>>(Zb, coords, weights,
                                                               ubuf, vbuf, hdrbuf, recs);
        splat2_kernel<<<NIMG * BANDS * CHUNKS, 1024, 0, stream>>>(recs, img);
    } else {
        splat_kernel<<<(NPTS + 255) / 256, 256, 0, stream>>>(z_x, z_y, z_z, Zb, coords,
                                                             weights, R, shifts, img);
    }

    // fused blur + row FFT
    fft_rows_fwd_blur_kernel<<<NIMG * NBOX / 2, 256, 0, stream>>>(img, freq);
    // 8-column fused col-FFT * ctf * inv-col-FFT
    fft_cols_ctf8_kernel<<<NIMG * 32, 1024, 0, stream>>>(freq, ctf);
    // inverse row FFT -> real out
    fft_rows_inv_kernel<<<NIMG * NBOX / 2, 256, 0, stream>>>(freq, out);
}

// Round 17
// 167.111 us; speedup vs baseline: 4.1141x; 1.0832x over previous
//
#include <hip/hip_runtime.h>
#include <hip/hip_bf16.h>

#define NIMG 32
#define NPTS 300000
#define NL   64
#define NBOX 256

#define BANDS  4
#define BROWS  64          // NBOX / BANDS
#define CHUNKS 2
#define CHPTS  (NPTS / CHUNKS)   // 150000

#define WQS  2047.0f             // 11-bit weight quantization scale (16-bit field headroom)
#define WQI  (1.0f / 2047.0f)

typedef float v2f __attribute__((ext_vector_type(2)));
typedef unsigned long long u64;

__device__ __forceinline__ int rev8(int x) { return (int)(__brev((unsigned)x) >> 24); }

// ---------------- zero fill ----------------
__global__ __launch_bounds__(256) void zero_kernel(float4* p, int n4) {
    int i = blockIdx.x * 256 + threadIdx.x;
    if (i < n4) p[i] = make_float4(0.f, 0.f, 0.f, 0.f);
}

// ---------------- P0: per-image fused coefficients ----------------
__global__ __launch_bounds__(256) void uvprep_kernel(
    const float* __restrict__ z_x, const float* __restrict__ z_y,
    const float* __restrict__ z_z, const float* __restrict__ R,
    const float* __restrict__ shifts,
    float* __restrict__ ubuf, float* __restrict__ vbuf, float4* __restrict__ hdrbuf)
{
    int t = threadIdx.x;
    for (int e = t; e < NIMG * NL; e += 256) {
        int b = e >> 6;
        const float* Rb = R + b * 9;
        float zx = z_x[e], zy = z_y[e], zz = z_z[e];
        ubuf[e] = Rb[0] * zx + Rb[1] * zy + Rb[2] * zz;
        vbuf[e] = Rb[3] * zx + Rb[4] * zy + Rb[5] * zz;
    }
    if (t < NIMG) {
        const float* Rb = R + t * 9;
        hdrbuf[2 * t]     = make_float4(Rb[0], Rb[1], Rb[2], shifts[2 * t]     + 128.f);
        hdrbuf[2 * t + 1] = make_float4(Rb[3], Rb[4], Rb[5], shifts[2 * t + 1] + 128.f);
    }
}

// ---------------- P1: projection -> one u64 record per (image,point) ----------------
// u/v/hdr read from GLOBAL with wave-uniform addresses -> scalar s_load path
// (K$ broadcast), bypassing the DS pipe that bound the LDS-staged version.
// rec = pos(16) | w00q<<16 | w10q<<28 | w01q<<40 | w11q<<52
__global__ __launch_bounds__(256) void project_kernel(
    const float* __restrict__ Zb, const float* __restrict__ coords,
    const float* __restrict__ weights,
    const float* __restrict__ ubuf, const float* __restrict__ vbuf,
    const float4* __restrict__ hdrbuf,
    u64* __restrict__ recs)
{
    int tid = threadIdx.x;
    int p = blockIdx.x * 256 + tid;
    if (p >= NPTS) return;

    v2f zr[32];
    {
        const float4* Zr4 = (const float4*)(Zb + (size_t)p * NL);
        float4 tmp[16];
        #pragma unroll
        for (int i = 0; i < 16; ++i) tmp[i] = Zr4[i];
        const v2f* t2 = (const v2f*)tmp;
        #pragma unroll
        for (int i = 0; i < 32; ++i) zr[i] = t2[i];
    }

    float cx0 = coords[3 * p + 0];
    float cy0 = coords[3 * p + 1];
    float cz0 = coords[3 * p + 2];
    float w   = weights[p];

    for (int b = 0; b < NIMG; ++b) {
        float4 h0 = hdrbuf[2 * b], h1 = hdrbuf[2 * b + 1];
        const v2f* u2 = (const v2f*)(ubuf + b * NL);
        const v2f* v2 = (const v2f*)(vbuf + b * NL);
        v2f ax = {0.f, 0.f}, ay = {0.f, 0.f};
        #pragma unroll
        for (int i = 0; i < 32; ++i) {
            ax += u2[i] * zr[i];
            ay += v2[i] * zr[i];
        }
        float px = fmaf(h0.x, cx0, fmaf(h0.y, cy0, fmaf(h0.z, cz0, h0.w))) + ax.x + ax.y;
        float py = fmaf(h1.x, cx0, fmaf(h1.y, cy0, fmaf(h1.z, cz0, h1.w))) + ay.x + ay.y;

        float x0f = floorf(px), y0f = floorf(py);
        float fx = px - x0f, fy = py - y0f;
        int xi0 = min(max((int)x0f, 0), NBOX - 1);
        int yi0 = min(max((int)y0f, 0), NBOX - 1);
        float w00 = w * (1.f - fx) * (1.f - fy);
        float w10 = w * fx * (1.f - fy);
        float w01 = w * (1.f - fx) * fy;
        float w11 = w * fx * fy;
        if (xi0 == NBOX - 1) {        // xi1 clamps onto xi0: fold right column left
            w00 += w10; w10 = 0.f;
            w01 += w11; w11 = 0.f;
        }
        if (yi0 == NBOX - 1) {        // yi1 clamps onto yi0: fold bottom row up
            w00 += w01; w01 = 0.f;
            w10 += w11; w11 = 0.f;
        }
        u64 rec = (u64)(unsigned)(xi0 | (yi0 << 8))
                | ((u64)(unsigned)(w00 * WQS + 0.5f) << 16)
                | ((u64)(unsigned)(w10 * WQS + 0.5f) << 28)
                | ((u64)(unsigned)(w01 * WQS + 0.5f) << 40)
                | ((u64)(unsigned)(w11 * WQS + 0.5f) << 52);
        recs[(size_t)b * NPTS + p] = rec;
    }
}

// ---------------- P2: band splat, ONE 2x2-quad u64 atomic per point-image ----------------
// BANDS=4, BROWS=64, quad views total 128.5 KB LDS, 1024-thread blocks (1 block/CU).
__global__ __launch_bounds__(1024) void splat2_kernel(
    const u64* __restrict__ recs, float* __restrict__ img)
{
    __shared__ u64 VA[32 * 128];   // 32 KB
    __shared__ u64 VB[32 * 129];   // 32.25 KB
    __shared__ u64 VC[32 * 128];   // 32 KB
    __shared__ u64 VD[32 * 129];   // 32.25 KB
    int tid = threadIdx.x;
    int id = blockIdx.x;           // band*64 + b*CHUNKS + c  (256 blocks)
    int band = id >> 6;            // 0..3
    int g    = id & 63;
    int b = g >> 1, c = g & 1;

    for (int i = tid; i < 32 * 128; i += 1024) { VA[i] = 0ULL; VC[i] = 0ULL; }
    for (int i = tid; i < 32 * 129; i += 1024) { VB[i] = 0ULL; VD[i] = 0ULL; }
    __syncthreads();

    const int y_lo = band * BROWS;
    const u64* rp = recs + (size_t)b * NPTS + (size_t)c * CHPTS;

    for (int i = 4 * tid; i < CHPTS; i += 4096) {
        ulonglong2 R01 = *(const ulonglong2*)(rp + i);       // points i, i+1
        ulonglong2 R23 = *(const ulonglong2*)(rp + i + 2);   // points i+2, i+3
        u64 Ra[4] = {R01.x, R01.y, R23.x, R23.y};
        #pragma unroll
        for (int k = 0; k < 4; ++k) {
            u64 rec = Ra[k];
            unsigned ps = (unsigned)rec & 0xFFFFu;
            int xi0 = ps & 255;
            int yi0 = ps >> 8;
            int r0 = yi0 - y_lo;
            if ((unsigned)r0 >= BROWS) continue;   // single ownership test
            u64 val = ((rec >> 16) & 0xFFFULL)
                    | (((rec >> 28) & 0xFFFULL) << 16)
                    | (((rec >> 40) & 0xFFFULL) << 32)
                    | (((rec >> 52) & 0xFFFULL) << 48);
            int qr = r0 >> 1;
            int qc = (xi0 + (xi0 & 1)) >> 1;
            bool xodd = (xi0 & 1), yodd = (r0 & 1);
            u64* base = yodd ? (xodd ? VD : VC) : (xodd ? VB : VA);
            int stride = xodd ? 129 : 128;
            atomicAdd(&base[qr * stride + qc], val);
        }
    }
    __syncthreads();
    // flush 65 rows (incl. halo row 64) with global atomic add
    int nrows = min(BROWS + 1, NBOX - y_lo);
    float* ib = img + (size_t)b * NBOX * NBOX + (size_t)y_lo * NBOX;
    for (int i = tid; i < nrows * NBOX; i += 1024) {
        int r = i >> 8, x = i & 255;
        int fc0 = x & 1;          // col field in VA/VC
        int fc1 = fc0 ^ 1;        // col field in VB/VD
        int ja = x >> 1;
        int jb = (x + 1) >> 1;
        unsigned acc = 0;
        if (r < BROWS) {
            int fr = (r & 1) << 1;
            acc += (unsigned)((VA[(r >> 1) * 128 + ja] >> (16 * (fr | fc0))) & 0xFFFFu);
            acc += (unsigned)((VB[(r >> 1) * 129 + jb] >> (16 * (fr | fc1))) & 0xFFFFu);
        }
        if (r >= 1) {
            int fr = ((r & 1) ^ 1) << 1;
            acc += (unsigned)((VC[((r - 1) >> 1) * 128 + ja] >> (16 * (fr | fc0))) & 0xFFFFu);
            acc += (unsigned)((VD[((r - 1) >> 1) * 129 + jb] >> (16 * (fr | fc1))) & 0xFFFFu);
        }
        if (acc) unsafeAtomicAdd(ib + i, (float)acc * WQI);
    }
}

// ---------------- fallback: fused splat with global atomics (small ws) ----------------
__global__ __launch_bounds__(256) void splat_kernel(
    const float* __restrict__ z_x, const float* __restrict__ z_y,
    const float* __restrict__ z_z, const float* __restrict__ Zb,
    const float* __restrict__ coords, const float* __restrict__ weights,
    const float* __restrict__ R, const float* __restrict__ shifts,
    float* __restrict__ img)
{
    __shared__ float s_z[3][NIMG][NL];
    __shared__ float s_R[NIMG][9];
    __shared__ float s_sh[NIMG][2];

    int tid = threadIdx.x;
    for (int i = tid; i < NIMG * NL; i += 256) {
        (&s_z[0][0][0])[i] = z_x[i];
        (&s_z[1][0][0])[i] = z_y[i];
        (&s_z[2][0][0])[i] = z_z[i];
    }
    for (int i = tid; i < NIMG * 9; i += 256) (&s_R[0][0])[i] = R[i];
    if (tid < NIMG * 2) (&s_sh[0][0])[tid] = shifts[tid];
    __syncthreads();

    int p = blockIdx.x * 256 + tid;
    if (p >= NPTS) return;

    float4 zr[16];
    const float4* Zr4 = (const float4*)(Zb + (size_t)p * NL);
    #pragma unroll
    for (int i = 0; i < 16; ++i) zr[i] = Zr4[i];

    float cx0 = coords[3 * p + 0];
    float cy0 = coords[3 * p + 1];
    float cz0 = coords[3 * p + 2];
    float w   = weights[p];

    for (int b = 0; b < NIMG; ++b) {
        const float4* zx4 = (const float4*)s_z[0][b];
        const float4* zy4 = (const float4*)s_z[1][b];
        const float4* zz4 = (const float4*)s_z[2][b];
        float dx = 0.f, dy = 0.f, dz = 0.f;
        #pragma unroll
        for (int i = 0; i < 16; ++i) {
            float4 a = zx4[i];
            dx += a.x * zr[i].x + a.y * zr[i].y + a.z * zr[i].z + a.w * zr[i].w;
            float4 bb = zy4[i];
            dy += bb.x * zr[i].x + bb.y * zr[i].y + bb.z * zr[i].z + bb.w * zr[i].w;
            float4 c = zz4[i];
            dz += c.x * zr[i].x + c.y * zr[i].y + c.z * zr[i].z + c.w * zr[i].w;
        }
        float cx = cx0 + dx, cy = cy0 + dy, cz = cz0 + dz;
        const float* Rb = s_R[b];
        float px = Rb[0] * cx + Rb[1] * cy + Rb[2] * cz + s_sh[b][0] + 128.0f;
        float py = Rb[3] * cx + Rb[4] * cy + Rb[5] * cz + s_sh[b][1] + 128.0f;

        float x0 = floorf(px), y0 = floorf(py);
        float fx = px - x0, fy = py - y0;
        int xi0 = min(max((int)x0, 0), NBOX - 1);
        int yi0 = min(max((int)y0, 0), NBOX - 1);
        int xi1 = min(xi0 + 1, NBOX - 1);
        int yi1 = min(yi0 + 1, NBOX - 1);

        float* ib = img + (size_t)b * NBOX * NBOX;
        unsafeAtomicAdd(ib + yi0 * NBOX + xi0, w * (1.f - fx) * (1.f - fy));
        unsafeAtomicAdd(ib + yi0 * NBOX + xi1, w * fx * (1.f - fy));
        unsafeAtomicAdd(ib + yi1 * NBOX + xi0, w * (1.f - fx) * fy);
        unsafeAtomicAdd(ib + yi1 * NBOX + xi1, w * fx * fy);
    }
}

// ---------------- 256-pt FFT helpers (AOS float2, LDS twiddle) ----------------
__device__ __forceinline__ void fft_dif_t(float2* s, const float2* tw, int t) {
    #pragma unroll
    for (int st = 7; st >= 0; --st) {
        int half = 1 << st;
        int j  = t & (half - 1);
        int i1 = ((t >> st) << (st + 1)) + j;
        int i2 = i1 + half;
        float2 a = s[i1], b = s[i2];
        float2 w = tw[j << (7 - st)];
        float dxr = a.x - b.x, dxi = a.y - b.y;
        s[i1] = make_float2(a.x + b.x, a.y + b.y);
        s[i2] = make_float2(w.x * dxr - w.y * dxi, w.x * dxi + w.y * dxr);
        __syncthreads();
    }
}

__device__ __forceinline__ void fft_dit_t(float2* s, const float2* tw, int t) {
    #pragma unroll
    for (int st = 0; st < 8; ++st) {
        int half = 1 << st;
        int j  = t & (half - 1);
        int i1 = ((t >> st) << (st + 1)) + j;
        int i2 = i1 + half;
        float2 a = s[i1], b = s[i2];
        float2 w = tw[j << (7 - st)];
        float cs = w.x, sn = -w.y;
        float tr = cs * b.x - sn * b.y;
        float ti = cs * b.y + sn * b.x;
        s[i1] = make_float2(a.x + tr, a.y + ti);
        s[i2] = make_float2(a.x - tr, a.y - ti);
        __syncthreads();
    }
}

// ---------------- SOA FFT helpers (8-col kernel) ----------------
__device__ __forceinline__ void fft_dif_soa(float* re, float* im, const float2* tw, int t) {
    #pragma unroll
    for (int st = 7; st >= 0; --st) {
        int half = 1 << st;
        int j  = t & (half - 1);
        int i1 = ((t >> st) << (st + 1)) + j;
        int i2 = i1 + half;
        float ar = re[i1], ai = im[i1], br = re[i2], bi = im[i2];
        float2 w = tw[j << (7 - st)];
        float dr = ar - br, di = ai - bi;
        re[i1] = ar + br;  im[i1] = ai + bi;
        re[i2] = w.x * dr - w.y * di;
        im[i2] = w.x * di + w.y * dr;
        __syncthreads();
    }
}

__device__ __forceinline__ void fft_dit_soa(float* re, float* im, const float2* tw, int t) {
    #pragma unroll
    for (int st = 0; st < 8; ++st) {
        int half = 1 << st;
        int j  = t & (half - 1);
        int i1 = ((t >> st) << (st + 1)) + j;
        int i2 = i1 + half;
        float ar = re[i1], ai = im[i1], br = re[i2], bi = im[i2];
        float2 w = tw[j << (7 - st)];
        float cs = w.x, sn = -w.y;
        float tr = cs * br - sn * bi;
        float ti = cs * bi + sn * br;
        re[i1] = ar + tr;  im[i1] = ai + ti;
        re[i2] = ar - tr;  im[i2] = ai - ti;
        __syncthreads();
    }
}

__device__ __forceinline__ void init_tw(float2* tw, int tid) {
    if (tid < 128) {
        float sn, cs;
        sincosf(-6.283185307179586f * (float)tid * (1.0f / 256.0f), &sn, &cs);
        tw[tid] = make_float2(cs, sn);
    }
}

// ---------------- Pass A: fused 5x5 blur + forward row FFT ----------------
__global__ __launch_bounds__(256) void fft_rows_fwd_blur_kernel(const float* __restrict__ img,
                                                                float2* __restrict__ freq)
{
    __shared__ float2 s[2][NBOX];
    __shared__ float  sb[2][NBOX];
    __shared__ float2 tw[128];
    int tid = threadIdx.x;
    int tx = tid & 127, ty = tid >> 7;
    init_tw(tw, tid);
    int row = blockIdx.x * 2 + ty;     // 0 .. B*N-1
    int b = row >> 8, y = row & (NBOX - 1);
    const float* ib = img + ((size_t)b << 16);
    const float gw[5] = {0.0544886845f, 0.2442013420f, 0.4026199469f,
                         0.2442013420f, 0.0544886845f};
    float acc0 = 0.f, acc1 = 0.f;
    #pragma unroll
    for (int dy = -2; dy <= 2; ++dy) {
        int yy = y + dy;
        if ((unsigned)yy < (unsigned)NBOX) {
            const float* rp = ib + yy * NBOX;
            acc0 += gw[dy + 2] * rp[tx];
            acc1 += gw[dy + 2] * rp[tx + 128];
        }
    }
    sb[ty][tx] = acc0;  sb[ty][tx + 128] = acc1;
    __syncthreads();
    float r0 = 0.f, r1 = 0.f;
    #pragma unroll
    for (int dx = -2; dx <= 2; ++dx) {
        int x0 = tx + dx, x1 = tx + 128 + dx;
        if ((unsigned)x0 < (unsigned)NBOX) r0 += gw[dx + 2] * sb[ty][x0];
        if ((unsigned)x1 < (unsigned)NBOX) r1 += gw[dx + 2] * sb[ty][x1];
    }
    s[ty][tx]       = make_float2(r0, 0.f);
    s[ty][tx + 128] = make_float2(r1, 0.f);
    __syncthreads();
    fft_dif_t(s[ty], tw, tx);
    float2* op = freq + (size_t)row * NBOX;
    op[tx]       = s[ty][tx];
    op[tx + 128] = s[ty][tx + 128];
}

// ---------------- Pass B: 8-column fused fwd-FFT * ctf * inv-FFT ----------------
__global__ __launch_bounds__(1024) void fft_cols_ctf8_kernel(float2* __restrict__ freq,
                                                             const float* __restrict__ ctf)
{
    __shared__ float  s_re[8][257];
    __shared__ float  s_im[8][257];
    __shared__ float2 tw[128];
    int tid = threadIdx.x;
    init_tw(tw, tid);
    int col = tid & 7, j = tid >> 3;          // j in 0..127
    int blk = blockIdx.x;
    int b = blk >> 5;
    int x = ((blk & 31) << 3) + col;          // storage x
    float2* base = freq + ((size_t)b << 16) + x;

    float2 v0 = base[(size_t)j * NBOX];
    float2 v1 = base[(size_t)(j + 128) * NBOX];
    s_re[col][j] = v0.x;        s_im[col][j] = v0.y;
    s_re[col][j + 128] = v1.x;  s_im[col][j + 128] = v1.y;
    __syncthreads();

    fft_dif_soa(s_re[col], s_im[col], tw, j);

    const float* cb = ctf + ((size_t)b << 16) + rev8(x);
    float c0 = cb[rev8(j) * NBOX];
    float c1 = cb[rev8(j + 128) * NBOX];
    s_re[col][j] *= c0;        s_im[col][j] *= c0;
    s_re[col][j + 128] *= c1;  s_im[col][j + 128] *= c1;
    __syncthreads();

    fft_dit_soa(s_re[col], s_im[col], tw, j);

    const float inv = 1.0f / 256.0f;
    base[(size_t)j * NBOX]         = make_float2(s_re[col][j] * inv, s_im[col][j] * inv);
    base[(size_t)(j + 128) * NBOX] = make_float2(s_re[col][j + 128] * inv, s_im[col][j + 128] * inv);
}

// ---------------- Pass C: inverse row FFT -> real output ----------------
__global__ __launch_bounds__(256) void fft_rows_inv_kernel(const float2* __restrict__ freq,
                                                           float* __restrict__ out)
{
    __shared__ float2 s[2][NBOX];
    __shared__ float2 tw[128];
    int tid = threadIdx.x;
    int tx = tid & 127, ty = tid >> 7;
    init_tw(tw, tid);
    int row = blockIdx.x * 2 + ty;
    const float2* rp = freq + (size_t)row * NBOX;
    s[ty][tx]       = rp[tx];
    s[ty][tx + 128] = rp[tx + 128];
    __syncthreads();
    fft_dit_t(s[ty], tw, tx);
    const float inv = 1.0f / 256.0f;
    out[(size_t)row * NBOX + tx]       = s[ty][tx].x * inv;
    out[(size_t)row * NBOX + tx + 128] = s[ty][tx + 128].x * inv;
}

extern "C" void kernel_launch(void* const* d_in, const int* in_sizes, int n_in,
                              void* d_out, int out_size, void* d_ws, size_t ws_size,
                              hipStream_t stream)
{
    (void)in_sizes; (void)n_in; (void)out_size;
    const float* z_x     = (const float*)d_in[0];
    const float* z_y     = (const float*)d_in[1];
    const float* z_z     = (const float*)d_in[2];
    const float* Zb      = (const float*)d_in[3];
    const float* coords  = (const float*)d_in[4];
    const float* weights = (const float*)d_in[5];
    const float* R       = (const float*)d_in[6];
    const float* shifts  = (const float*)d_in[7];
    const float* ctf     = (const float*)d_in[8];
    float* out = (float*)d_out;

    const size_t NELEM = (size_t)NIMG * NBOX * NBOX;           // 2,097,152
    const size_t NPAIR = (size_t)NIMG * NPTS;                  // 9.6 M
    char* base = (char*)d_ws;
    float* img  = (float*)base;                                 // 8 MB
    u64*   recs = (u64*)(base + 8388608);                       // 76.8 MB
    float* ubuf = (float*)(base + 8388608 + 76800000);          // 8 KB
    float* vbuf = ubuf + NIMG * NL;                             // 8 KB
    float4* hdrbuf = (float4*)(vbuf + NIMG * NL);               // 1 KB
    // freq aliases recs (recs dead after splat2; freq written after)
    float2* freq = (float2*)(base + 8388608);                   // 16.78 MB < 76.8 MB
    const size_t required = 8388608 + 76800000 + NIMG * NL * 8 + NIMG * 2 * 16;

    zero_kernel<<<(int)(NELEM / 4 + 255) / 256, 256, 0, stream>>>((float4*)img, (int)(NELEM / 4));

    if (ws_size >= required) {
        uvprep_kernel<<<1, 256, 0, stream>>>(z_x, z_y, z_z, R, shifts, ubuf, vbuf, hdrbuf);
        project_kernel<<<(NPTS + 255) / 256, 256, 0, stream>>>(Zb, coords, weights,
                                                               ubuf, vbuf, hdrbuf, recs);
        splat2_kernel<<<NIMG * BANDS * CHUNKS, 1024, 0, stream>>>(recs, img);
    } else {
        splat_kernel<<<(NPTS + 255) / 256, 256, 0, stream>>>(z_x, z_y, z_z, Zb, coords,
                                                             weights, R, shifts, img);
    }

    // fused blur + row FFT
    fft_rows_fwd_blur_kernel<<<NIMG * NBOX / 2, 256, 0, stream>>>(img, freq);
    // 8-column fused col-FFT * ctf * inv-col-FFT
    fft_cols_ctf8_kernel<<<NIMG * 32, 1024, 0, stream>>>(freq, ctf);
    // inverse row FFT -> real out
    fft_rows_inv_kernel<<<NIMG * NBOX / 2, 256, 0, stream>>>(freq, out);
}